// Round 1
// baseline (657.929 us; speedup 1.0000x reference)
//
#include <hip/hip_runtime.h>
#include <hip/hip_bf16.h>

#define T_TOK 4096
#define HD 1024
#define ID 2048
#define NE 8

#define BM 128
#define BN 128
#define BK 64

typedef __attribute__((ext_vector_type(8))) __bf16 bf16x8;
typedef __attribute__((ext_vector_type(4))) float f32x4;
typedef __attribute__((ext_vector_type(4))) unsigned int u32x4;

__device__ __forceinline__ unsigned short f2bf(float f) {
  __hip_bfloat16 h = __float2bfloat16(f);
  return __builtin_bit_cast(unsigned short, h);
}
__device__ __forceinline__ unsigned int pk2(float lo, float hi) {
  return (unsigned int)f2bf(lo) | ((unsigned int)f2bf(hi) << 16);
}

// ---------------- routing ----------------
__global__ void k_zero(int* cnt) { if (threadIdx.x < 32) cnt[threadIdx.x] = 0; }

__global__ __launch_bounds__(256) void k_route(const float* __restrict__ x,
    const float* __restrict__ gw, const float* __restrict__ bias,
    int* __restrict__ cnt, int* __restrict__ tokens, float* __restrict__ wts)
{
  const int lane = threadIdx.x & 63;
  const int t = blockIdx.x * 4 + (threadIdx.x >> 6);
  const float* xr = x + (size_t)t * HD + lane * 16;
  f32x4 xv[4];
  #pragma unroll
  for (int j = 0; j < 4; ++j) xv[j] = *(const f32x4*)(xr + j * 4);
  float sc[NE];
  #pragma unroll
  for (int e = 0; e < NE; ++e) {
    const float* gr = gw + e * HD + lane * 16;
    float a = 0.f;
    #pragma unroll
    for (int j = 0; j < 4; ++j) {
      f32x4 gv = *(const f32x4*)(gr + j * 4);
      a += xv[j][0]*gv[0] + xv[j][1]*gv[1] + xv[j][2]*gv[2] + xv[j][3]*gv[3];
    }
    #pragma unroll
    for (int off = 32; off > 0; off >>= 1) a += __shfl_xor(a, off);
    sc[e] = a;
  }
  // top-2 of biased scores (selection), lowest index wins ties
  int i1 = 0; float b1 = sc[0] + bias[0];
  #pragma unroll
  for (int e = 1; e < NE; ++e) { float be = sc[e] + bias[e]; if (be > b1) { b1 = be; i1 = e; } }
  int i2 = -1; float b2 = -3e38f;
  #pragma unroll
  for (int e = 0; e < NE; ++e) { if (e == i1) continue; float be = sc[e] + bias[e]; if (be > b2) { b2 = be; i2 = e; } }
  // top-2 raw VALUES (weights)
  int a1 = 0; float r1 = sc[0];
  #pragma unroll
  for (int e = 1; e < NE; ++e) if (sc[e] > r1) { r1 = sc[e]; a1 = e; }
  float r2 = -3e38f;
  #pragma unroll
  for (int e = 0; e < NE; ++e) if (e != a1 && sc[e] > r2) r2 = sc[e];
  float w1 = 1.f / (1.f + __expf(-r1));
  float w2 = 1.f / (1.f + __expf(-r2));
  float s = w1 + w2; w1 /= s; w2 /= s;
  if (lane == 0) {
    int p = atomicAdd(&cnt[i1], 1); tokens[i1 * T_TOK + p] = t; wts[i1 * T_TOK + p] = w1;
    p = atomicAdd(&cnt[i2], 1);     tokens[i2 * T_TOK + p] = t; wts[i2 * T_TOK + p] = w2;
  }
}

__global__ void k_fin(const int* __restrict__ cnt, int* __restrict__ base, float* __restrict__ out)
{
  if (threadIdx.x == 0) {
    int b = 0, mx = 0;
    #pragma unroll
    for (int e = 0; e < NE; ++e) { base[e] = b; b += cnt[e]; if (cnt[e] > mx) mx = cnt[e]; }
    base[NE] = b;
    out[(size_t)T_TOK * HD] = (float)mx * (1.f / 1024.f) - 1.f;  // viol
  }
}

// ---------------- GEMM1: act = silu(x@Wg) * (x@Wu), gathered rows ----------------
__global__ __launch_bounds__(256) void k_mlp1(
    const float* __restrict__ x,
    const float* __restrict__ Wg, const float* __restrict__ Wu,
    const float* __restrict__ Sg, const float* __restrict__ Su,
    const int* __restrict__ cnt, const int* __restrict__ base,
    const int* __restrict__ tokens,
    unsigned short* __restrict__ act)
{
  __shared__ __attribute__((aligned(16))) unsigned short Al[BM * BK];
  __shared__ __attribute__((aligned(16))) unsigned short Bgl[BN * BK];
  __shared__ __attribute__((aligned(16))) unsigned short Bul[BN * BK];

  const int e = blockIdx.z;
  const int cntE = (e == NE) ? T_TOK : cnt[e];
  const int m0 = blockIdx.y * BM;
  if (m0 >= cntE) return;
  const int n0 = blockIdx.x * BN;
  const float* Bg = (e == NE) ? Sg : (Wg + (size_t)e * HD * ID);
  const float* Bu = (e == NE) ? Su : (Wu + (size_t)e * HD * ID);
  const int rowbase = (e == NE) ? 2 * T_TOK : base[e];
  const int tid = threadIdx.x;

  const int akg = tid & 7;                 // A stage: k-group
  int arow[4];
  #pragma unroll
  for (int it = 0; it < 4; ++it) {
    int r = (tid >> 3) + it * 32;
    int rl = min(m0 + r, cntE - 1);        // clamp: never read poisoned list slots
    arow[it] = (e == NE) ? rl : tokens[e * T_TOK + rl];
  }
  const int bn_ = tid & 127;               // B stage: column
  const int bkg0 = tid >> 7;

  f32x4 accg[4][4], accu[4][4];
  const f32x4 z4 = {0.f, 0.f, 0.f, 0.f};
  #pragma unroll
  for (int i = 0; i < 4; ++i)
    #pragma unroll
    for (int j = 0; j < 4; ++j) { accg[i][j] = z4; accu[i][j] = z4; }

  const int lane = tid & 63;
  const int wid = tid >> 6;
  const int wm = (wid >> 1) * 64, wn = (wid & 1) * 64;
  const int lr = lane & 15, lg = lane >> 4;

  for (int k0 = 0; k0 < HD; k0 += BK) {
    #pragma unroll
    for (int it = 0; it < 4; ++it) {
      int r = (tid >> 3) + it * 32;
      const float* src = x + (size_t)arow[it] * HD + k0 + akg * 8;
      f32x4 v0 = *(const f32x4*)src;
      f32x4 v1 = *(const f32x4*)(src + 4);
      u32x4 pk = { pk2(v0[0], v0[1]), pk2(v0[2], v0[3]), pk2(v1[0], v1[1]), pk2(v1[2], v1[3]) };
      *(u32x4*)&Al[r * BK + ((akg ^ (r & 7)) * 8)] = pk;
    }
    #pragma unroll
    for (int m = 0; m < 2; ++m) {
      const float* Bsrc = m ? Bu : Bg;
      unsigned short* Bl = m ? Bul : Bgl;
      #pragma unroll
      for (int it = 0; it < 4; ++it) {
        int kg = bkg0 + it * 2;
        const float* src = Bsrc + (size_t)(k0 + kg * 8) * ID + n0 + bn_;
        float f[8];
        #pragma unroll
        for (int j = 0; j < 8; ++j) f[j] = src[(size_t)j * ID];
        u32x4 pk = { pk2(f[0], f[1]), pk2(f[2], f[3]), pk2(f[4], f[5]), pk2(f[6], f[7]) };
        *(u32x4*)&Bl[bn_ * BK + ((kg ^ (bn_ & 7)) * 8)] = pk;
      }
    }
    __syncthreads();
    #pragma unroll
    for (int kk = 0; kk < 2; ++kk) {
      bf16x8 a[4];
      #pragma unroll
      for (int am = 0; am < 4; ++am) {
        int row = wm + am * 16 + lr;
        a[am] = *(const bf16x8*)&Al[row * BK + (((kk * 4 + lg) ^ (row & 7)) * 8)];
      }
      #pragma unroll
      for (int bn = 0; bn < 4; ++bn) {
        int c = wn + bn * 16 + lr;
        int so = c * BK + (((kk * 4 + lg) ^ (c & 7)) * 8);
        bf16x8 bg = *(const bf16x8*)&Bgl[so];
        bf16x8 bu = *(const bf16x8*)&Bul[so];
        #pragma unroll
        for (int am = 0; am < 4; ++am) {
          accg[am][bn] = __builtin_amdgcn_mfma_f32_16x16x32_bf16(a[am], bg, accg[am][bn], 0, 0, 0);
          accu[am][bn] = __builtin_amdgcn_mfma_f32_16x16x32_bf16(a[am], bu, accu[am][bn], 0, 0, 0);
        }
      }
    }
    __syncthreads();
  }
  #pragma unroll
  for (int am = 0; am < 4; ++am) {
    #pragma unroll
    for (int bn = 0; bn < 4; ++bn) {
      f32x4 gv = accg[am][bn], uv = accu[am][bn];
      int col = n0 + wn + bn * 16 + lr;
      #pragma unroll
      for (int q = 0; q < 4; ++q) {
        int r = wm + am * 16 + lg * 4 + q;
        if (m0 + r < cntE) {
          float g = gv[q], u = uv[q];
          float val = (g / (1.f + __expf(-g))) * u;
          act[(size_t)(rowbase + m0 + r) * ID + col] = f2bf(val);
        }
      }
    }
  }
}

// ---------------- GEMM2: out += w * (act @ Wd) ----------------
template<bool STORE>
__global__ __launch_bounds__(256) void k_mlp2(
    const unsigned short* __restrict__ act,
    const float* __restrict__ Wd, const float* __restrict__ Sd,
    const int* __restrict__ cnt, const int* __restrict__ base,
    const int* __restrict__ tokens, const float* __restrict__ wts,
    float* __restrict__ out)
{
  __shared__ __attribute__((aligned(16))) unsigned short Al[BM * BK];
  __shared__ __attribute__((aligned(16))) unsigned short Bl[BN * BK];
  const int e = STORE ? NE : blockIdx.z;
  const int cntE = STORE ? T_TOK : cnt[e];
  const int m0 = blockIdx.y * BM;
  if (m0 >= cntE) return;
  const int n0 = blockIdx.x * BN;
  const float* B = STORE ? Sd : (Wd + (size_t)e * ID * HD);
  const int rowbase = STORE ? 2 * T_TOK : base[e];
  const int tid = threadIdx.x;
  const int akg = tid & 7;
  int arow[4];
  #pragma unroll
  for (int it = 0; it < 4; ++it) {
    int r = (tid >> 3) + it * 32;
    arow[it] = rowbase + min(m0 + r, cntE - 1);
  }
  const int bn_ = tid & 127;
  const int bkg0 = tid >> 7;
  f32x4 acc[4][4];
  const f32x4 z4 = {0.f, 0.f, 0.f, 0.f};
  #pragma unroll
  for (int i = 0; i < 4; ++i)
    #pragma unroll
    for (int j = 0; j < 4; ++j) acc[i][j] = z4;
  const int lane = tid & 63;
  const int wid = tid >> 6;
  const int wm = (wid >> 1) * 64, wn = (wid & 1) * 64;
  const int lr = lane & 15, lg = lane >> 4;

  for (int k0 = 0; k0 < ID; k0 += BK) {
    #pragma unroll
    for (int it = 0; it < 4; ++it) {
      int r = (tid >> 3) + it * 32;
      const unsigned short* src = act + (size_t)arow[it] * ID + k0 + akg * 8;
      u32x4 v = *(const u32x4*)src;
      *(u32x4*)&Al[r * BK + ((akg ^ (r & 7)) * 8)] = v;
    }
    #pragma unroll
    for (int it = 0; it < 4; ++it) {
      int kg = bkg0 + it * 2;
      const float* src = B + (size_t)(k0 + kg * 8) * HD + n0 + bn_;
      float f[8];
      #pragma unroll
      for (int j = 0; j < 8; ++j) f[j] = src[(size_t)j * HD];
      u32x4 pk = { pk2(f[0], f[1]), pk2(f[2], f[3]), pk2(f[4], f[5]), pk2(f[6], f[7]) };
      *(u32x4*)&Bl[bn_ * BK + ((kg ^ (bn_ & 7)) * 8)] = pk;
    }
    __syncthreads();
    #pragma unroll
    for (int kk = 0; kk < 2; ++kk) {
      bf16x8 a[4];
      #pragma unroll
      for (int am = 0; am < 4; ++am) {
        int row = wm + am * 16 + lr;
        a[am] = *(const bf16x8*)&Al[row * BK + (((kk * 4 + lg) ^ (row & 7)) * 8)];
      }
      #pragma unroll
      for (int bn = 0; bn < 4; ++bn) {
        int c = wn + bn * 16 + lr;
        bf16x8 b = *(const bf16x8*)&Bl[c * BK + (((kk * 4 + lg) ^ (c & 7)) * 8)];
        #pragma unroll
        for (int am = 0; am < 4; ++am)
          acc[am][bn] = __builtin_amdgcn_mfma_f32_16x16x32_bf16(a[am], b, acc[am][bn], 0, 0, 0);
      }
    }
    __syncthreads();
  }
  #pragma unroll
  for (int am = 0; am < 4; ++am) {
    #pragma unroll
    for (int bn = 0; bn < 4; ++bn) {
      f32x4 av = acc[am][bn];
      int col = n0 + wn + bn * 16 + lr;
      #pragma unroll
      for (int q = 0; q < 4; ++q) {
        int r = wm + am * 16 + lg * 4 + q;
        int rl = m0 + r;
        if (rl < cntE) {
          if (STORE) {
            out[(size_t)rl * HD + col] = av[q];     // shared expert: token == row
          } else {
            int t = tokens[e * T_TOK + rl];
            float w = wts[e * T_TOK + rl];
            atomicAdd(out + (size_t)t * HD + col, av[q] * w);
          }
        }
      }
    }
  }
}

extern "C" void kernel_launch(void* const* d_in, const int* in_sizes, int n_in,
                              void* d_out, int out_size, void* d_ws, size_t ws_size,
                              hipStream_t stream)
{
  const float* x    = (const float*)d_in[0];
  const float* gw   = (const float*)d_in[1];
  const float* bias = (const float*)d_in[2];
  const float* Wg   = (const float*)d_in[3];
  const float* Wu   = (const float*)d_in[4];
  const float* Wd   = (const float*)d_in[5];
  const float* Sg   = (const float*)d_in[6];
  const float* Su   = (const float*)d_in[7];
  const float* Sd   = (const float*)d_in[8];
  float* out = (float*)d_out;
  char* ws = (char*)d_ws;

  int*   cnt    = (int*)ws;                               // 16 ints
  int*   base   = cnt + 16;                               // 16 ints
  int*   tokens = (int*)(ws + 128);                       // 8*4096 ints
  float* wts    = (float*)(ws + 128 + NE * T_TOK * 4);    // 8*4096 floats
  unsigned short* act = (unsigned short*)(ws + (1 << 19)); // 12288 x 2048 bf16 (~48 MB)

  k_zero<<<dim3(1), dim3(64), 0, stream>>>(cnt);
  k_route<<<dim3(T_TOK / 4), dim3(256), 0, stream>>>(x, gw, bias, cnt, tokens, wts);
  k_fin<<<dim3(1), dim3(64), 0, stream>>>(cnt, base, out);
  k_mlp1<<<dim3(ID / BN, T_TOK / BM, NE + 1), dim3(256), 0, stream>>>(x, Wg, Wu, Sg, Su, cnt, base, tokens, act);
  k_mlp2<true ><<<dim3(HD / BN, T_TOK / BM, 1),  dim3(256), 0, stream>>>(act, Wd, Sd, cnt, base, tokens, wts, out);
  k_mlp2<false><<<dim3(HD / BN, T_TOK / BM, NE), dim3(256), 0, stream>>>(act, Wd, Sd, cnt, base, tokens, wts, out);
}

// Round 2
// 592.306 us; speedup vs baseline: 1.1108x; 1.1108x over previous
//
#include <hip/hip_runtime.h>
#include <hip/hip_bf16.h>

#define T_TOK 4096
#define HD 1024
#define ID 2048
#define NE 8

#define BM 128
#define BN 128
#define BK 64

typedef __attribute__((ext_vector_type(8))) __bf16 bf16x8;
typedef __attribute__((ext_vector_type(4))) float f32x4;
typedef __attribute__((ext_vector_type(4))) unsigned int u32x4;

#define AS1 __attribute__((address_space(1)))
#define AS3 __attribute__((address_space(3)))

__device__ __forceinline__ unsigned short f2bf(float f) {
  __hip_bfloat16 h = __float2bfloat16(f);
  return __builtin_bit_cast(unsigned short, h);
}
__device__ __forceinline__ unsigned int pk2(float lo, float hi) {
  return (unsigned int)f2bf(lo) | ((unsigned int)f2bf(hi) << 16);
}
// async global->LDS, 16B per lane. lds dest must be wave-uniform base (+lane*16 implicit).
__device__ __forceinline__ void gl16(const void* g, void* l) {
  __builtin_amdgcn_global_load_lds((const AS1 unsigned int*)g, (AS3 unsigned int*)l, 16, 0, 0);
}

// ---------------- routing ----------------
__global__ void k_zero(int* cnt) { if (threadIdx.x < 32) cnt[threadIdx.x] = 0; }

__global__ __launch_bounds__(256) void k_route(const float* __restrict__ x,
    const float* __restrict__ gw, const float* __restrict__ bias,
    int* __restrict__ cnt, int* __restrict__ tokens, float* __restrict__ wts)
{
  const int lane = threadIdx.x & 63;
  const int t = blockIdx.x * 4 + (threadIdx.x >> 6);
  const float* xr = x + (size_t)t * HD + lane * 16;
  f32x4 xv[4];
  #pragma unroll
  for (int j = 0; j < 4; ++j) xv[j] = *(const f32x4*)(xr + j * 4);
  float sc[NE];
  #pragma unroll
  for (int e = 0; e < NE; ++e) {
    const float* gr = gw + e * HD + lane * 16;
    float a = 0.f;
    #pragma unroll
    for (int j = 0; j < 4; ++j) {
      f32x4 gv = *(const f32x4*)(gr + j * 4);
      a += xv[j][0]*gv[0] + xv[j][1]*gv[1] + xv[j][2]*gv[2] + xv[j][3]*gv[3];
    }
    #pragma unroll
    for (int off = 32; off > 0; off >>= 1) a += __shfl_xor(a, off);
    sc[e] = a;
  }
  int i1 = 0; float b1 = sc[0] + bias[0];
  #pragma unroll
  for (int e = 1; e < NE; ++e) { float be = sc[e] + bias[e]; if (be > b1) { b1 = be; i1 = e; } }
  int i2 = -1; float b2 = -3e38f;
  #pragma unroll
  for (int e = 0; e < NE; ++e) { if (e == i1) continue; float be = sc[e] + bias[e]; if (be > b2) { b2 = be; i2 = e; } }
  int a1 = 0; float r1 = sc[0];
  #pragma unroll
  for (int e = 1; e < NE; ++e) if (sc[e] > r1) { r1 = sc[e]; a1 = e; }
  float r2 = -3e38f;
  #pragma unroll
  for (int e = 0; e < NE; ++e) if (e != a1 && sc[e] > r2) r2 = sc[e];
  float w1 = 1.f / (1.f + __expf(-r1));
  float w2 = 1.f / (1.f + __expf(-r2));
  float s = w1 + w2; w1 /= s; w2 /= s;
  if (lane == 0) {
    int p = atomicAdd(&cnt[i1], 1); tokens[i1 * T_TOK + p] = t; wts[i1 * T_TOK + p] = w1;
    p = atomicAdd(&cnt[i2], 1);     tokens[i2 * T_TOK + p] = t; wts[i2 * T_TOK + p] = w2;
  }
}

__global__ void k_fin(const int* __restrict__ cnt, int* __restrict__ base, float* __restrict__ out)
{
  if (threadIdx.x == 0) {
    int b = 0, mx = 0;
    #pragma unroll
    for (int e = 0; e < NE; ++e) { base[e] = b; b += cnt[e]; if (cnt[e] > mx) mx = cnt[e]; }
    base[NE] = b;
    out[(size_t)T_TOK * HD] = (float)mx * (1.f / 1024.f) - 1.f;  // viol
  }
}

// ---------------- converts ----------------
__global__ __launch_bounds__(256) void k_cvtx(const float* __restrict__ x, unsigned short* __restrict__ xb) {
  size_t i = ((size_t)blockIdx.x * 256 + threadIdx.x) * 8;
  f32x4 v0 = *(const f32x4*)(x + i), v1 = *(const f32x4*)(x + i + 4);
  u32x4 pk = { pk2(v0[0],v0[1]), pk2(v0[2],v0[3]), pk2(v1[0],v1[1]), pk2(v1[2],v1[3]) };
  *(u32x4*)&xb[i] = pk;
}

// src [K][N] fp32 -> dst [N][K] bf16 (batched over z). 64x64 tiles, coalesced reads,
// 16B stores (write combining handled by L2).
__global__ __launch_bounds__(256) void k_tcvt(const float* __restrict__ src0, unsigned short* __restrict__ dst0,
                                              int K, int N)
{
  const float* src = src0 + (size_t)blockIdx.z * K * N;
  unsigned short* dst = dst0 + (size_t)blockIdx.z * K * N;
  const int k0 = blockIdx.y * 64, n0 = blockIdx.x * 64;
  const int n = threadIdx.x & 63, kg = threadIdx.x >> 6;  // kg 0..3
  #pragma unroll
  for (int it = 0; it < 2; ++it) {
    int kb = k0 + (it * 4 + kg) * 8;
    float f[8];
    #pragma unroll
    for (int j = 0; j < 8; ++j) f[j] = src[(size_t)(kb + j) * N + n0 + n];
    u32x4 pk = { pk2(f[0],f[1]), pk2(f[2],f[3]), pk2(f[4],f[5]), pk2(f[6],f[7]) };
    *(u32x4*)&dst[(size_t)(n0 + n) * K + kb] = pk;
  }
}

// ---------------- GEMM1: act = silu(x@Wg) * (x@Wu), gathered rows, m97-style ----------------
// LDS layout: [row][64k] bf16 linear (global_load_lds), k-slot s of row r holds k-group s^(r&7)
// (pre-swizzled global source), so fragment reads are conflict-free ds_read_b128.
__global__ __launch_bounds__(256) void k_mlp1(
    const unsigned short* __restrict__ xb,
    const unsigned short* __restrict__ WgT, const unsigned short* __restrict__ WuT,
    const unsigned short* __restrict__ SgT, const unsigned short* __restrict__ SuT,
    const int* __restrict__ cnt, const int* __restrict__ base,
    const int* __restrict__ tokens,
    unsigned short* __restrict__ act)
{
  __shared__ __attribute__((aligned(16))) unsigned short Al[BM * BK];
  __shared__ __attribute__((aligned(16))) unsigned short Bgl[BN * BK];
  __shared__ __attribute__((aligned(16))) unsigned short Bul[BN * BK];

  const int e = blockIdx.z;
  const int cntE = (e == NE) ? T_TOK : cnt[e];
  const int m0 = blockIdx.y * BM;
  if (m0 >= cntE) return;
  const int n0 = blockIdx.x * BN;
  const unsigned short* Bg = (e == NE) ? SgT : WgT + (size_t)e * HD * ID;
  const unsigned short* Bu = (e == NE) ? SuT : WuT + (size_t)e * HD * ID;
  const int rowbase = (e == NE) ? 2 * T_TOK : base[e];
  const int tid = threadIdx.x, lane = tid & 63, w = tid >> 6;
  const int l3 = lane >> 3;                  // row within 8-row group == r&7
  const int kgf = (lane & 7) ^ l3;           // pre-swizzled fetch k-group

  size_t aoff[4], boff[4];
  #pragma unroll
  for (int it = 0; it < 4; ++it) {
    int r = w * 32 + it * 8 + l3;
    int rl = min(m0 + r, cntE - 1);
    int tok = (e == NE) ? rl : tokens[e * T_TOK + rl];
    aoff[it] = ((size_t)tok * HD + (size_t)kgf * 8) * 2;
    boff[it] = ((size_t)(n0 + r) * HD + (size_t)kgf * 8) * 2;
  }

  f32x4 accg[4][4], accu[4][4];
  const f32x4 z4 = {0.f, 0.f, 0.f, 0.f};
  #pragma unroll
  for (int i = 0; i < 4; ++i)
    #pragma unroll
    for (int j = 0; j < 4; ++j) { accg[i][j] = z4; accu[i][j] = z4; }

  const int lr = lane & 15, lg = lane >> 4;
  const int wm = (w >> 1) * 64, wn = (w & 1) * 64;

  for (int k0 = 0; k0 < HD; k0 += BK) {
    size_t kb = (size_t)k0 * 2;
    #pragma unroll
    for (int it = 0; it < 4; ++it) gl16((const char*)xb + aoff[it] + kb, Al  + (w * 4 + it) * 512);
    #pragma unroll
    for (int it = 0; it < 4; ++it) gl16((const char*)Bg + boff[it] + kb, Bgl + (w * 4 + it) * 512);
    #pragma unroll
    for (int it = 0; it < 4; ++it) gl16((const char*)Bu + boff[it] + kb, Bul + (w * 4 + it) * 512);
    __syncthreads();
    #pragma unroll
    for (int kk = 0; kk < 2; ++kk) {
      const int q = kk * 4 + lg;
      bf16x8 a[4], bg[4], bu[4];
      #pragma unroll
      for (int am = 0; am < 4; ++am) {
        int r = wm + am * 16 + lr;
        a[am] = *(const bf16x8*)&Al[r * BK + ((q ^ (r & 7)) * 8)];
      }
      #pragma unroll
      for (int bn = 0; bn < 4; ++bn) {
        int c = wn + bn * 16 + lr;
        int so = c * BK + ((q ^ (c & 7)) * 8);
        bg[bn] = *(const bf16x8*)&Bgl[so];
        bu[bn] = *(const bf16x8*)&Bul[so];
      }
      #pragma unroll
      for (int bn = 0; bn < 4; ++bn)
        #pragma unroll
        for (int am = 0; am < 4; ++am) {
          accg[am][bn] = __builtin_amdgcn_mfma_f32_16x16x32_bf16(a[am], bg[bn], accg[am][bn], 0, 0, 0);
          accu[am][bn] = __builtin_amdgcn_mfma_f32_16x16x32_bf16(a[am], bu[bn], accu[am][bn], 0, 0, 0);
        }
    }
    __syncthreads();
  }
  #pragma unroll
  for (int am = 0; am < 4; ++am) {
    #pragma unroll
    for (int bn = 0; bn < 4; ++bn) {
      f32x4 gv = accg[am][bn], uv = accu[am][bn];
      int col = n0 + wn + bn * 16 + lr;
      #pragma unroll
      for (int q = 0; q < 4; ++q) {
        int r = wm + am * 16 + lg * 4 + q;
        if (m0 + r < cntE) {
          float g = gv[q], u = uv[q];
          float val = (g / (1.f + __expf(-g))) * u;
          act[(size_t)(rowbase + m0 + r) * ID + col] = f2bf(val);
        }
      }
    }
  }
}

// ---------------- GEMM2: out += w * (act @ Wd), m97-style ----------------
template<bool STORE>
__global__ __launch_bounds__(256) void k_mlp2(
    const unsigned short* __restrict__ act,
    const unsigned short* __restrict__ WdT, const unsigned short* __restrict__ SdT,
    const int* __restrict__ cnt, const int* __restrict__ base,
    const int* __restrict__ tokens, const float* __restrict__ wts,
    float* __restrict__ out)
{
  __shared__ __attribute__((aligned(16))) unsigned short Al[BM * BK];
  __shared__ __attribute__((aligned(16))) unsigned short Bl[BN * BK];
  const int e = STORE ? NE : blockIdx.z;
  const int cntE = STORE ? T_TOK : cnt[e];
  const int m0 = blockIdx.y * BM;
  if (m0 >= cntE) return;
  const int n0 = blockIdx.x * BN;
  const unsigned short* B = STORE ? SdT : WdT + (size_t)e * ID * HD;
  const int rowbase = STORE ? 2 * T_TOK : base[e];
  const int tid = threadIdx.x, lane = tid & 63, w = tid >> 6;
  const int l3 = lane >> 3;
  const int kgf = (lane & 7) ^ l3;

  size_t aoff[4], boff[4];
  #pragma unroll
  for (int it = 0; it < 4; ++it) {
    int r = w * 32 + it * 8 + l3;
    int rl = rowbase + min(m0 + r, cntE - 1);
    aoff[it] = ((size_t)rl * ID + (size_t)kgf * 8) * 2;
    boff[it] = ((size_t)(n0 + r) * ID + (size_t)kgf * 8) * 2;
  }

  f32x4 acc[4][4];
  const f32x4 z4 = {0.f, 0.f, 0.f, 0.f};
  #pragma unroll
  for (int i = 0; i < 4; ++i)
    #pragma unroll
    for (int j = 0; j < 4; ++j) acc[i][j] = z4;

  const int lr = lane & 15, lg = lane >> 4;
  const int wm = (w >> 1) * 64, wn = (w & 1) * 64;

  for (int k0 = 0; k0 < ID; k0 += BK) {
    size_t kb = (size_t)k0 * 2;
    #pragma unroll
    for (int it = 0; it < 4; ++it) gl16((const char*)act + aoff[it] + kb, Al + (w * 4 + it) * 512);
    #pragma unroll
    for (int it = 0; it < 4; ++it) gl16((const char*)B + boff[it] + kb, Bl + (w * 4 + it) * 512);
    __syncthreads();
    #pragma unroll
    for (int kk = 0; kk < 2; ++kk) {
      const int q = kk * 4 + lg;
      bf16x8 a[4], b[4];
      #pragma unroll
      for (int am = 0; am < 4; ++am) {
        int r = wm + am * 16 + lr;
        a[am] = *(const bf16x8*)&Al[r * BK + ((q ^ (r & 7)) * 8)];
      }
      #pragma unroll
      for (int bn = 0; bn < 4; ++bn) {
        int c = wn + bn * 16 + lr;
        b[bn] = *(const bf16x8*)&Bl[c * BK + ((q ^ (c & 7)) * 8)];
      }
      #pragma unroll
      for (int bn = 0; bn < 4; ++bn)
        #pragma unroll
        for (int am = 0; am < 4; ++am)
          acc[am][bn] = __builtin_amdgcn_mfma_f32_16x16x32_bf16(a[am], b[bn], acc[am][bn], 0, 0, 0);
    }
    __syncthreads();
  }
  #pragma unroll
  for (int am = 0; am < 4; ++am) {
    #pragma unroll
    for (int bn = 0; bn < 4; ++bn) {
      f32x4 av = acc[am][bn];
      int col = n0 + wn + bn * 16 + lr;
      #pragma unroll
      for (int q = 0; q < 4; ++q) {
        int r = wm + am * 16 + lg * 4 + q;
        int rl = m0 + r;
        if (rl < cntE) {
          if (STORE) {
            out[(size_t)rl * HD + col] = av[q];
          } else {
            int t = tokens[e * T_TOK + rl];
            float wgt = wts[e * T_TOK + rl];
            atomicAdd(out + (size_t)t * HD + col, av[q] * wgt);
          }
        }
      }
    }
  }
}

extern "C" void kernel_launch(void* const* d_in, const int* in_sizes, int n_in,
                              void* d_out, int out_size, void* d_ws, size_t ws_size,
                              hipStream_t stream)
{
  const float* x    = (const float*)d_in[0];
  const float* gw   = (const float*)d_in[1];
  const float* bias = (const float*)d_in[2];
  const float* Wg   = (const float*)d_in[3];
  const float* Wu   = (const float*)d_in[4];
  const float* Wd   = (const float*)d_in[5];
  const float* Sg   = (const float*)d_in[6];
  const float* Su   = (const float*)d_in[7];
  const float* Sd   = (const float*)d_in[8];
  float* out = (float*)d_out;
  char* ws = (char*)d_ws;

  int*   cnt    = (int*)ws;
  int*   base   = cnt + 16;
  int*   tokens = (int*)(ws + 128);
  float* wts    = (float*)(ws + 128 + NE * T_TOK * 4);

  size_t o = (size_t)1 << 19;
  unsigned short* xbf = (unsigned short*)(ws + o); o += (size_t)T_TOK * HD * 2;
  unsigned short* WgT = (unsigned short*)(ws + o); o += (size_t)NE * HD * ID * 2;
  unsigned short* WuT = (unsigned short*)(ws + o); o += (size_t)NE * HD * ID * 2;
  unsigned short* WdT = (unsigned short*)(ws + o); o += (size_t)NE * HD * ID * 2;
  unsigned short* SgT = (unsigned short*)(ws + o); o += (size_t)HD * ID * 2;
  unsigned short* SuT = (unsigned short*)(ws + o); o += (size_t)HD * ID * 2;
  unsigned short* SdT = (unsigned short*)(ws + o); o += (size_t)HD * ID * 2;
  unsigned short* actb = (unsigned short*)(ws + o);  // 12288 x 2048 bf16

  k_zero<<<dim3(1), dim3(64), 0, stream>>>(cnt);
  k_cvtx<<<dim3(T_TOK * HD / 2048), dim3(256), 0, stream>>>(x, xbf);
  k_tcvt<<<dim3(ID / 64, HD / 64, NE), dim3(256), 0, stream>>>(Wg, WgT, HD, ID);
  k_tcvt<<<dim3(ID / 64, HD / 64, NE), dim3(256), 0, stream>>>(Wu, WuT, HD, ID);
  k_tcvt<<<dim3(HD / 64, ID / 64, NE), dim3(256), 0, stream>>>(Wd, WdT, ID, HD);
  k_tcvt<<<dim3(ID / 64, HD / 64, 1),  dim3(256), 0, stream>>>(Sg, SgT, HD, ID);
  k_tcvt<<<dim3(ID / 64, HD / 64, 1),  dim3(256), 0, stream>>>(Su, SuT, HD, ID);
  k_tcvt<<<dim3(HD / 64, ID / 64, 1),  dim3(256), 0, stream>>>(Sd, SdT, ID, HD);
  k_route<<<dim3(T_TOK / 4), dim3(256), 0, stream>>>(x, gw, bias, cnt, tokens, wts);
  k_fin<<<dim3(1), dim3(64), 0, stream>>>(cnt, base, out);
  k_mlp1<<<dim3(ID / BN, T_TOK / BM, NE + 1), dim3(256), 0, stream>>>(xbf, WgT, WuT, SgT, SuT, cnt, base, tokens, actb);
  k_mlp2<true ><<<dim3(HD / BN, T_TOK / BM, 1),  dim3(256), 0, stream>>>(actb, WdT, SdT, cnt, base, tokens, wts, out);
  k_mlp2<false><<<dim3(HD / BN, T_TOK / BM, NE), dim3(256), 0, stream>>>(actb, WdT, SdT, cnt, base, tokens, wts, out);
}

// Round 3
// 490.860 us; speedup vs baseline: 1.3404x; 1.2067x over previous
//
#include <hip/hip_runtime.h>
#include <hip/hip_bf16.h>

#define T_TOK 4096
#define HD 1024
#define ID 2048
#define NE 8

#define BM 128
#define BN 128
#define BK 64
#define BK1 32

typedef __attribute__((ext_vector_type(8))) __bf16 bf16x8;
typedef __attribute__((ext_vector_type(4))) float f32x4;
typedef __attribute__((ext_vector_type(4))) unsigned int u32x4;
typedef __attribute__((ext_vector_type(2))) unsigned int u32x2;

#define AS1 __attribute__((address_space(1)))
#define AS3 __attribute__((address_space(3)))

__device__ __forceinline__ unsigned short f2bf(float f) {
  __hip_bfloat16 h = __float2bfloat16(f);
  return __builtin_bit_cast(unsigned short, h);
}
__device__ __forceinline__ unsigned int pk2(float lo, float hi) {
  return (unsigned int)f2bf(lo) | ((unsigned int)f2bf(hi) << 16);
}
__device__ __forceinline__ float bflo(unsigned int u) { return __builtin_bit_cast(float, u << 16); }
__device__ __forceinline__ float bfhi(unsigned int u) { return __builtin_bit_cast(float, u & 0xffff0000u); }
// async global->LDS, 16B per lane; LDS dest wave-uniform base (+lane*16 implicit)
__device__ __forceinline__ void gl16(const void* g, void* l) {
  __builtin_amdgcn_global_load_lds((const AS1 unsigned int*)g, (AS3 unsigned int*)l, 16, 0, 0);
}

// ---------------- routing ----------------
__global__ void k_zero(int* cnt) { if (threadIdx.x < 32) cnt[threadIdx.x] = 0; }

__global__ __launch_bounds__(256) void k_route(const float* __restrict__ x,
    const float* __restrict__ gw, const float* __restrict__ bias,
    int* __restrict__ cnt, int* __restrict__ tokens, float* __restrict__ wts,
    int* __restrict__ slotrec)
{
  const int lane = threadIdx.x & 63;
  const int t = blockIdx.x * 4 + (threadIdx.x >> 6);
  const float* xr = x + (size_t)t * HD + lane * 16;
  f32x4 xv[4];
  #pragma unroll
  for (int j = 0; j < 4; ++j) xv[j] = *(const f32x4*)(xr + j * 4);
  float sc[NE];
  #pragma unroll
  for (int e = 0; e < NE; ++e) {
    const float* gr = gw + e * HD + lane * 16;
    float a = 0.f;
    #pragma unroll
    for (int j = 0; j < 4; ++j) {
      f32x4 gv = *(const f32x4*)(gr + j * 4);
      a += xv[j][0]*gv[0] + xv[j][1]*gv[1] + xv[j][2]*gv[2] + xv[j][3]*gv[3];
    }
    #pragma unroll
    for (int off = 32; off > 0; off >>= 1) a += __shfl_xor(a, off);
    sc[e] = a;
  }
  int i1 = 0; float b1 = sc[0] + bias[0];
  #pragma unroll
  for (int e = 1; e < NE; ++e) { float be = sc[e] + bias[e]; if (be > b1) { b1 = be; i1 = e; } }
  int i2 = -1; float b2 = -3e38f;
  #pragma unroll
  for (int e = 0; e < NE; ++e) { if (e == i1) continue; float be = sc[e] + bias[e]; if (be > b2) { b2 = be; i2 = e; } }
  int a1 = 0; float r1 = sc[0];
  #pragma unroll
  for (int e = 1; e < NE; ++e) if (sc[e] > r1) { r1 = sc[e]; a1 = e; }
  float r2 = -3e38f;
  #pragma unroll
  for (int e = 0; e < NE; ++e) if (e != a1 && sc[e] > r2) r2 = sc[e];
  float w1 = 1.f / (1.f + __expf(-r1));
  float w2 = 1.f / (1.f + __expf(-r2));
  float s = w1 + w2; w1 /= s; w2 /= s;
  if (lane == 0) {
    int p = atomicAdd(&cnt[i1], 1); tokens[i1 * T_TOK + p] = t; wts[i1 * T_TOK + p] = w1;
    slotrec[t * 2] = (i1 << 16) | p;
    p = atomicAdd(&cnt[i2], 1);     tokens[i2 * T_TOK + p] = t; wts[i2 * T_TOK + p] = w2;
    slotrec[t * 2 + 1] = (i2 << 16) | p;
  }
}

__global__ void k_fin(const int* __restrict__ cnt, int* __restrict__ base, float* __restrict__ out)
{
  if (threadIdx.x == 0) {
    int b = 0, mx = 0;
    #pragma unroll
    for (int e = 0; e < NE; ++e) { base[e] = b; b += cnt[e]; if (cnt[e] > mx) mx = cnt[e]; }
    base[NE] = b;
    out[(size_t)T_TOK * HD] = (float)mx * (1.f / 1024.f) - 1.f;  // viol
  }
}

// ---------------- converts ----------------
__global__ __launch_bounds__(256) void k_cvtx(const float* __restrict__ x, unsigned short* __restrict__ xb) {
  size_t i = ((size_t)blockIdx.x * 256 + threadIdx.x) * 8;
  f32x4 v0 = *(const f32x4*)(x + i), v1 = *(const f32x4*)(x + i + 4);
  u32x4 pk = { pk2(v0[0],v0[1]), pk2(v0[2],v0[3]), pk2(v1[0],v1[1]), pk2(v1[2],v1[3]) };
  *(u32x4*)&xb[i] = pk;
}

// src [K][N] fp32 -> dst [N][K] bf16 (batched over z)
__global__ __launch_bounds__(256) void k_tcvt(const float* __restrict__ src0, unsigned short* __restrict__ dst0,
                                              int K, int N)
{
  const float* src = src0 + (size_t)blockIdx.z * K * N;
  unsigned short* dst = dst0 + (size_t)blockIdx.z * K * N;
  const int k0 = blockIdx.y * 64, n0 = blockIdx.x * 64;
  const int n = threadIdx.x & 63, kg = threadIdx.x >> 6;
  #pragma unroll
  for (int it = 0; it < 2; ++it) {
    int kb = k0 + (it * 4 + kg) * 8;
    float f[8];
    #pragma unroll
    for (int j = 0; j < 8; ++j) f[j] = src[(size_t)(kb + j) * N + n0 + n];
    u32x4 pk = { pk2(f[0],f[1]), pk2(f[2],f[3]), pk2(f[4],f[5]), pk2(f[6],f[7]) };
    *(u32x4*)&dst[(size_t)(n0 + n) * K + kb] = pk;
  }
}

// ---------------- GEMM1: act = silu(x@Wg) * (x@Wu), 2-phase dbuf, BK=32 ----------------
// LDS [row][32k]: slot s of row r holds global k-group s ^ ((r>>1)&3).
__global__ __launch_bounds__(256) void k_mlp1(
    const unsigned short* __restrict__ xb,
    const unsigned short* __restrict__ WgT, const unsigned short* __restrict__ WuT,
    const unsigned short* __restrict__ SgT, const unsigned short* __restrict__ SuT,
    const int* __restrict__ cnt, const int* __restrict__ base,
    const int* __restrict__ tokens,
    unsigned short* __restrict__ act)
{
  __shared__ __attribute__((aligned(16))) unsigned short Al[2][BM * BK1];
  __shared__ __attribute__((aligned(16))) unsigned short Bgl[2][BN * BK1];
  __shared__ __attribute__((aligned(16))) unsigned short Bul[2][BN * BK1];

  const int e = blockIdx.z;
  const int cntE = (e == NE) ? T_TOK : cnt[e];
  const int m0 = blockIdx.y * BM;
  if (m0 >= cntE) return;
  const int n0 = blockIdx.x * BN;
  const unsigned short* Bg = (e == NE) ? SgT : WgT + (size_t)e * HD * ID;
  const unsigned short* Bu = (e == NE) ? SuT : WuT + (size_t)e * HD * ID;
  const int rowbase = (e == NE) ? 2 * T_TOK : base[e];
  const int tid = threadIdx.x, lane = tid & 63, w = tid >> 6;
  const int sl = lane & 3;          // k-slot
  const int lrow = lane >> 2;       // row within 16-row instr group

  size_t aoff[2], boff[2];
  #pragma unroll
  for (int it = 0; it < 2; ++it) {
    int rloc = w * 32 + it * 16 + lrow;
    int kgf = sl ^ ((rloc >> 1) & 3);
    int rl = min(m0 + rloc, cntE - 1);
    int tok = (e == NE) ? rl : tokens[e * T_TOK + rl];
    aoff[it] = ((size_t)tok * HD + (size_t)kgf * 8) * 2;
    boff[it] = ((size_t)(n0 + rloc) * HD + (size_t)kgf * 8) * 2;
  }

  f32x4 accg[4][4], accu[4][4];
  const f32x4 z4 = {0.f, 0.f, 0.f, 0.f};
  #pragma unroll
  for (int i = 0; i < 4; ++i)
    #pragma unroll
    for (int j = 0; j < 4; ++j) { accg[i][j] = z4; accu[i][j] = z4; }

  const int lr = lane & 15, lg = lane >> 4;
  const int wm = (w >> 1) * 64, wn = (w & 1) * 64;

  #define STAGE1(ks, b) { \
    size_t kb = (size_t)(ks) * (BK1 * 2); \
    _Pragma("unroll") \
    for (int it = 0; it < 2; ++it) { \
      gl16((const char*)xb + aoff[it] + kb, &Al [b][(w * 32 + it * 16) * BK1]); \
      gl16((const char*)Bg + boff[it] + kb, &Bgl[b][(w * 32 + it * 16) * BK1]); \
      gl16((const char*)Bu + boff[it] + kb, &Bul[b][(w * 32 + it * 16) * BK1]); \
    } }

  STAGE1(0, 0);
  __syncthreads();
  int cur = 0;
  for (int ks = 0; ks < HD / BK1; ++ks) {
    if (ks + 1 < HD / BK1) STAGE1(ks + 1, cur ^ 1);
    bf16x8 a[4], bg[4], bu[4];
    #pragma unroll
    for (int am = 0; am < 4; ++am) {
      int r = wm + am * 16 + lr;
      a[am] = *(const bf16x8*)&Al[cur][r * BK1 + ((lg ^ ((r >> 1) & 3)) * 8)];
    }
    #pragma unroll
    for (int bn = 0; bn < 4; ++bn) {
      int c = wn + bn * 16 + lr;
      int so = c * BK1 + ((lg ^ ((c >> 1) & 3)) * 8);
      bg[bn] = *(const bf16x8*)&Bgl[cur][so];
      bu[bn] = *(const bf16x8*)&Bul[cur][so];
    }
    #pragma unroll
    for (int bn = 0; bn < 4; ++bn)
      #pragma unroll
      for (int am = 0; am < 4; ++am) {
        accg[am][bn] = __builtin_amdgcn_mfma_f32_16x16x32_bf16(a[am], bg[bn], accg[am][bn], 0, 0, 0);
        accu[am][bn] = __builtin_amdgcn_mfma_f32_16x16x32_bf16(a[am], bu[bn], accu[am][bn], 0, 0, 0);
      }
    __syncthreads();
    cur ^= 1;
  }
  #undef STAGE1

  #pragma unroll
  for (int am = 0; am < 4; ++am) {
    #pragma unroll
    for (int bn = 0; bn < 4; ++bn) {
      f32x4 gv = accg[am][bn], uv = accu[am][bn];
      int col = n0 + wn + bn * 16 + lr;
      #pragma unroll
      for (int q = 0; q < 4; ++q) {
        int r = wm + am * 16 + lg * 4 + q;
        if (m0 + r < cntE) {
          float g = gv[q], u = uv[q];
          float val = (g / (1.f + __expf(-g))) * u;
          act[(size_t)(rowbase + m0 + r) * ID + col] = f2bf(val);
        }
      }
    }
  }
}

// ---------------- GEMM2: dn[slot] = act[slot] @ Wd (plain bf16 stores), 2-phase dbuf ----------------
__global__ __launch_bounds__(256) void k_mlp2(
    const unsigned short* __restrict__ act,
    const unsigned short* __restrict__ WdT, const unsigned short* __restrict__ SdT,
    const int* __restrict__ cnt, const int* __restrict__ base,
    unsigned short* __restrict__ dn)
{
  __shared__ __attribute__((aligned(16))) unsigned short Al[2][BM * BK];
  __shared__ __attribute__((aligned(16))) unsigned short Bl[2][BN * BK];
  const int e = blockIdx.z;
  const int cntE = (e == NE) ? T_TOK : cnt[e];
  const int m0 = blockIdx.y * BM;
  if (m0 >= cntE) return;
  const int n0 = blockIdx.x * BN;
  const unsigned short* B = (e == NE) ? SdT : WdT + (size_t)e * ID * HD;
  const int rowbase = (e == NE) ? 2 * T_TOK : base[e];
  const int tid = threadIdx.x, lane = tid & 63, w = tid >> 6;
  const int l3 = lane >> 3;
  const int kgf = (lane & 7) ^ l3;

  size_t aoff[4], boff[4];
  #pragma unroll
  for (int it = 0; it < 4; ++it) {
    int rloc = w * 32 + it * 8 + l3;
    int rl = rowbase + min(m0 + rloc, cntE - 1);
    aoff[it] = ((size_t)rl * ID + (size_t)kgf * 8) * 2;
    boff[it] = ((size_t)(n0 + rloc) * ID + (size_t)kgf * 8) * 2;
  }

  f32x4 acc[4][4];
  const f32x4 z4 = {0.f, 0.f, 0.f, 0.f};
  #pragma unroll
  for (int i = 0; i < 4; ++i)
    #pragma unroll
    for (int j = 0; j < 4; ++j) acc[i][j] = z4;

  const int lr = lane & 15, lg = lane >> 4;
  const int wm = (w >> 1) * 64, wn = (w & 1) * 64;

  #define STAGE2(ks, b) { \
    size_t kb = (size_t)(ks) * (BK * 2); \
    _Pragma("unroll") \
    for (int it = 0; it < 4; ++it) { \
      gl16((const char*)act + aoff[it] + kb, &Al[b][(w * 4 + it) * 512]); \
      gl16((const char*)B   + boff[it] + kb, &Bl[b][(w * 4 + it) * 512]); \
    } }

  STAGE2(0, 0);
  __syncthreads();
  int cur = 0;
  for (int ks = 0; ks < ID / BK; ++ks) {
    if (ks + 1 < ID / BK) STAGE2(ks + 1, cur ^ 1);
    #pragma unroll
    for (int kk = 0; kk < 2; ++kk) {
      const int q = kk * 4 + lg;
      bf16x8 a[4], b[4];
      #pragma unroll
      for (int am = 0; am < 4; ++am) {
        int r = wm + am * 16 + lr;
        a[am] = *(const bf16x8*)&Al[cur][r * BK + ((q ^ (r & 7)) * 8)];
      }
      #pragma unroll
      for (int bn = 0; bn < 4; ++bn) {
        int c = wn + bn * 16 + lr;
        b[bn] = *(const bf16x8*)&Bl[cur][c * BK + ((q ^ (c & 7)) * 8)];
      }
      #pragma unroll
      for (int bn = 0; bn < 4; ++bn)
        #pragma unroll
        for (int am = 0; am < 4; ++am)
          acc[am][bn] = __builtin_amdgcn_mfma_f32_16x16x32_bf16(a[am], b[bn], acc[am][bn], 0, 0, 0);
    }
    __syncthreads();
    cur ^= 1;
  }
  #undef STAGE2

  #pragma unroll
  for (int am = 0; am < 4; ++am) {
    #pragma unroll
    for (int bn = 0; bn < 4; ++bn) {
      f32x4 av = acc[am][bn];
      int col = n0 + wn + bn * 16 + lr;
      #pragma unroll
      for (int q = 0; q < 4; ++q) {
        int r = wm + am * 16 + lg * 4 + q;
        if (m0 + r < cntE)
          dn[(size_t)(rowbase + m0 + r) * HD + col] = f2bf(av[q]);
      }
    }
  }
}

// ---------------- combine: out[t] = dn[shared_t] + w1*dn[s1] + w2*dn[s2] ----------------
__global__ __launch_bounds__(256) void k_comb(const unsigned short* __restrict__ dn,
    const int* __restrict__ base, const int* __restrict__ slotrec,
    const float* __restrict__ wts, float* __restrict__ out)
{
  const int t = blockIdx.x;
  const int c = threadIdx.x * 4;
  int r0 = slotrec[t * 2], r1 = slotrec[t * 2 + 1];
  int e0 = r0 >> 16, p0 = r0 & 0xffff;
  int e1 = r1 >> 16, p1 = r1 & 0xffff;
  int s0 = base[e0] + p0, s1 = base[e1] + p1;
  float w0 = wts[e0 * T_TOK + p0], w1 = wts[e1 * T_TOK + p1];
  u32x2 vs = *(const u32x2*)&dn[(size_t)(2 * T_TOK + t) * HD + c];
  u32x2 va = *(const u32x2*)&dn[(size_t)s0 * HD + c];
  u32x2 vb = *(const u32x2*)&dn[(size_t)s1 * HD + c];
  f32x4 o;
  o[0] = bflo(vs[0]) + w0 * bflo(va[0]) + w1 * bflo(vb[0]);
  o[1] = bfhi(vs[0]) + w0 * bfhi(va[0]) + w1 * bfhi(vb[0]);
  o[2] = bflo(vs[1]) + w0 * bflo(va[1]) + w1 * bflo(vb[1]);
  o[3] = bfhi(vs[1]) + w0 * bfhi(va[1]) + w1 * bfhi(vb[1]);
  *(f32x4*)&out[(size_t)t * HD + c] = o;
}

extern "C" void kernel_launch(void* const* d_in, const int* in_sizes, int n_in,
                              void* d_out, int out_size, void* d_ws, size_t ws_size,
                              hipStream_t stream)
{
  const float* x    = (const float*)d_in[0];
  const float* gw   = (const float*)d_in[1];
  const float* bias = (const float*)d_in[2];
  const float* Wg   = (const float*)d_in[3];
  const float* Wu   = (const float*)d_in[4];
  const float* Wd   = (const float*)d_in[5];
  const float* Sg   = (const float*)d_in[6];
  const float* Su   = (const float*)d_in[7];
  const float* Sd   = (const float*)d_in[8];
  float* out = (float*)d_out;
  char* ws = (char*)d_ws;

  int*   cnt     = (int*)ws;                                  // 16 ints
  int*   base    = cnt + 16;
  int*   tokens  = (int*)(ws + 512);                          // 8*4096 ints (128KB)
  float* wts     = (float*)(ws + 512 + (NE * T_TOK * 4));     // 128KB
  int*   slotrec = (int*)(ws + 512 + 2 * (NE * T_TOK * 4));   // 32KB

  size_t o = (size_t)1 << 20;
  unsigned short* xbf = (unsigned short*)(ws + o); o += (size_t)T_TOK * HD * 2;
  unsigned short* WgT = (unsigned short*)(ws + o); o += (size_t)NE * HD * ID * 2;
  unsigned short* WuT = (unsigned short*)(ws + o); o += (size_t)NE * HD * ID * 2;
  unsigned short* WdT = (unsigned short*)(ws + o); o += (size_t)NE * HD * ID * 2;
  unsigned short* SgT = (unsigned short*)(ws + o); o += (size_t)HD * ID * 2;
  unsigned short* SuT = (unsigned short*)(ws + o); o += (size_t)HD * ID * 2;
  unsigned short* SdT = (unsigned short*)(ws + o); o += (size_t)HD * ID * 2;
  unsigned short* actb = (unsigned short*)(ws + o); o += (size_t)3 * T_TOK * ID * 2;
  unsigned short* dn   = (unsigned short*)(ws + o);           // 12288 x 1024 bf16 (24MB)

  k_zero<<<dim3(1), dim3(64), 0, stream>>>(cnt);
  k_cvtx<<<dim3(T_TOK * HD / 2048), dim3(256), 0, stream>>>(x, xbf);
  k_tcvt<<<dim3(ID / 64, HD / 64, NE), dim3(256), 0, stream>>>(Wg, WgT, HD, ID);
  k_tcvt<<<dim3(ID / 64, HD / 64, NE), dim3(256), 0, stream>>>(Wu, WuT, HD, ID);
  k_tcvt<<<dim3(HD / 64, ID / 64, NE), dim3(256), 0, stream>>>(Wd, WdT, ID, HD);
  k_tcvt<<<dim3(ID / 64, HD / 64, 1),  dim3(256), 0, stream>>>(Sg, SgT, HD, ID);
  k_tcvt<<<dim3(ID / 64, HD / 64, 1),  dim3(256), 0, stream>>>(Su, SuT, HD, ID);
  k_tcvt<<<dim3(HD / 64, ID / 64, 1),  dim3(256), 0, stream>>>(Sd, SdT, ID, HD);
  k_route<<<dim3(T_TOK / 4), dim3(256), 0, stream>>>(x, gw, bias, cnt, tokens, wts, slotrec);
  k_fin<<<dim3(1), dim3(64), 0, stream>>>(cnt, base, out);
  k_mlp1<<<dim3(ID / BN, T_TOK / BM, NE + 1), dim3(256), 0, stream>>>(xbf, WgT, WuT, SgT, SuT, cnt, base, tokens, actb);
  k_mlp2<<<dim3(HD / BN, T_TOK / BM, NE + 1), dim3(256), 0, stream>>>(actb, WdT, SdT, cnt, base, dn);
  k_comb<<<dim3(T_TOK), dim3(256), 0, stream>>>(dn, base, slotrec, wts, out);
}

// Round 4
// 475.055 us; speedup vs baseline: 1.3850x; 1.0333x over previous
//
#include <hip/hip_runtime.h>
#include <hip/hip_bf16.h>

#define T_TOK 4096
#define HD 1024
#define ID 2048
#define NE 8

#define BM 128
#define BN 128
#define BK1 32

typedef __attribute__((ext_vector_type(8))) __bf16 bf16x8;
typedef __attribute__((ext_vector_type(4))) float f32x4;
typedef __attribute__((ext_vector_type(4))) unsigned int u32x4;
typedef __attribute__((ext_vector_type(2))) unsigned int u32x2;

#define AS1 __attribute__((address_space(1)))
#define AS3 __attribute__((address_space(3)))

#define WAITV(N) asm volatile("s_waitcnt vmcnt(" #N ")" ::: "memory")

__device__ __forceinline__ unsigned short f2bf(float f) {
  __hip_bfloat16 h = __float2bfloat16(f);
  return __builtin_bit_cast(unsigned short, h);
}
__device__ __forceinline__ unsigned int pk2(float lo, float hi) {
  return (unsigned int)f2bf(lo) | ((unsigned int)f2bf(hi) << 16);
}
__device__ __forceinline__ float bflo(unsigned int u) { return __builtin_bit_cast(float, u << 16); }
__device__ __forceinline__ float bfhi(unsigned int u) { return __builtin_bit_cast(float, u & 0xffff0000u); }
// async global->LDS, 16B per lane; LDS dest wave-uniform base (+lane*16 implicit)
__device__ __forceinline__ void gl16(const void* g, void* l) {
  __builtin_amdgcn_global_load_lds((const AS1 unsigned int*)g, (AS3 unsigned int*)l, 16, 0, 0);
}

// ---------------- routing ----------------
__global__ void k_zero(int* cnt) { if (threadIdx.x < 32) cnt[threadIdx.x] = 0; }

__global__ __launch_bounds__(256) void k_route(const float* __restrict__ x,
    const float* __restrict__ gw, const float* __restrict__ bias,
    int* __restrict__ cnt, int* __restrict__ tokens, float* __restrict__ wts,
    int* __restrict__ slotrec)
{
  const int lane = threadIdx.x & 63;
  const int t = blockIdx.x * 4 + (threadIdx.x >> 6);
  const float* xr = x + (size_t)t * HD + lane * 16;
  f32x4 xv[4];
  #pragma unroll
  for (int j = 0; j < 4; ++j) xv[j] = *(const f32x4*)(xr + j * 4);
  float sc[NE];
  #pragma unroll
  for (int e = 0; e < NE; ++e) {
    const float* gr = gw + e * HD + lane * 16;
    float a = 0.f;
    #pragma unroll
    for (int j = 0; j < 4; ++j) {
      f32x4 gv = *(const f32x4*)(gr + j * 4);
      a += xv[j][0]*gv[0] + xv[j][1]*gv[1] + xv[j][2]*gv[2] + xv[j][3]*gv[3];
    }
    #pragma unroll
    for (int off = 32; off > 0; off >>= 1) a += __shfl_xor(a, off);
    sc[e] = a;
  }
  int i1 = 0; float b1 = sc[0] + bias[0];
  #pragma unroll
  for (int e = 1; e < NE; ++e) { float be = sc[e] + bias[e]; if (be > b1) { b1 = be; i1 = e; } }
  int i2 = -1; float b2 = -3e38f;
  #pragma unroll
  for (int e = 0; e < NE; ++e) { if (e == i1) continue; float be = sc[e] + bias[e]; if (be > b2) { b2 = be; i2 = e; } }
  int a1 = 0; float r1 = sc[0];
  #pragma unroll
  for (int e = 1; e < NE; ++e) if (sc[e] > r1) { r1 = sc[e]; a1 = e; }
  float r2 = -3e38f;
  #pragma unroll
  for (int e = 0; e < NE; ++e) if (e != a1 && sc[e] > r2) r2 = sc[e];
  float w1 = 1.f / (1.f + __expf(-r1));
  float w2 = 1.f / (1.f + __expf(-r2));
  float s = w1 + w2; w1 /= s; w2 /= s;
  if (lane == 0) {
    int p = atomicAdd(&cnt[i1], 1); tokens[i1 * T_TOK + p] = t; wts[i1 * T_TOK + p] = w1;
    slotrec[t * 2] = (i1 << 16) | p;
    p = atomicAdd(&cnt[i2], 1);     tokens[i2 * T_TOK + p] = t; wts[i2 * T_TOK + p] = w2;
    slotrec[t * 2 + 1] = (i2 << 16) | p;
  }
}

__global__ void k_fin(const int* __restrict__ cnt, int* __restrict__ base, float* __restrict__ out)
{
  if (threadIdx.x == 0) {
    int b = 0, mx = 0;
    #pragma unroll
    for (int e = 0; e < NE; ++e) { base[e] = b; b += cnt[e]; if (cnt[e] > mx) mx = cnt[e]; }
    base[NE] = b;
    out[(size_t)T_TOK * HD] = (float)mx * (1.f / 1024.f) - 1.f;  // viol
  }
}

// ---------------- converts ----------------
__global__ __launch_bounds__(256) void k_cvtx(const float* __restrict__ x, unsigned short* __restrict__ xb) {
  size_t i = ((size_t)blockIdx.x * 256 + threadIdx.x) * 8;
  f32x4 v0 = *(const f32x4*)(x + i), v1 = *(const f32x4*)(x + i + 4);
  u32x4 pk = { pk2(v0[0],v0[1]), pk2(v0[2],v0[3]), pk2(v1[0],v1[1]), pk2(v1[2],v1[3]) };
  *(u32x4*)&xb[i] = pk;
}

// src [K][N] fp32 -> dst [N][K] bf16 (batched over z). LDS-transposed:
// coalesced 256B reads, XOR-swizzled LDS, coalesced 128B writes.
__global__ __launch_bounds__(256) void k_tcvt(const float* __restrict__ src0, unsigned short* __restrict__ dst0,
                                              int K, int N)
{
  __shared__ __attribute__((aligned(16))) unsigned short tl[64 * 64];
  const float* src = src0 + (size_t)blockIdx.z * K * N;
  unsigned short* dst = dst0 + (size_t)blockIdx.z * K * N;
  const int k0 = blockIdx.y * 64, n0 = blockIdx.x * 64;
  const int t = threadIdx.x;
  const int nc = (t & 15) * 4;
  #pragma unroll
  for (int it = 0; it < 4; ++it) {
    int kr = (t >> 4) + it * 16;
    f32x4 v = *(const f32x4*)&src[(size_t)(k0 + kr) * N + n0 + nc];
    #pragma unroll
    for (int j = 0; j < 4; ++j) {
      int n = nc + j;
      tl[n * 64 + (((kr >> 3) ^ (n & 7)) * 8) + (kr & 7)] = f2bf(v[j]);
    }
  }
  __syncthreads();
  #pragma unroll
  for (int it = 0; it < 2; ++it) {
    int idx = t + it * 256;
    int n = idx >> 3, kc8 = idx & 7;
    u32x4 v = *(const u32x4*)&tl[n * 64 + ((kc8 ^ (n & 7)) * 8)];
    *(u32x4*)&dst[(size_t)(n0 + n) * K + k0 + kc8 * 8] = v;
  }
}

// ---------------- GEMM1: act = silu(x@Wg) * (x@Wu), 3-buf counted-vmcnt, BK=32 ----------------
// LDS [row][32k]: slot s of row r holds global k-group s ^ ((r>>1)&3).
__global__ __launch_bounds__(256) void k_mlp1(
    const unsigned short* __restrict__ xb,
    const unsigned short* __restrict__ WgT, const unsigned short* __restrict__ WuT,
    const unsigned short* __restrict__ SgT, const unsigned short* __restrict__ SuT,
    const int* __restrict__ cnt, const int* __restrict__ base,
    const int* __restrict__ tokens,
    unsigned short* __restrict__ act)
{
  __shared__ __attribute__((aligned(16))) unsigned short Al [3][BM * BK1];
  __shared__ __attribute__((aligned(16))) unsigned short Bgl[3][BN * BK1];
  __shared__ __attribute__((aligned(16))) unsigned short Bul[3][BN * BK1];

  const int e = blockIdx.z;
  const int cntE = (e == NE) ? T_TOK : cnt[e];
  const int m0 = blockIdx.y * BM;
  if (m0 >= cntE) return;
  const int n0 = blockIdx.x * BN;
  const unsigned short* Bg = (e == NE) ? SgT : WgT + (size_t)e * HD * ID;
  const unsigned short* Bu = (e == NE) ? SuT : WuT + (size_t)e * HD * ID;
  const int rowbase = (e == NE) ? 2 * T_TOK : base[e];
  const int tid = threadIdx.x, lane = tid & 63, w = tid >> 6;
  const int sl = lane & 3;          // k-slot
  const int lrow = lane >> 2;       // row within 16-row group

  size_t aoff[2], boff[2];
  #pragma unroll
  for (int it = 0; it < 2; ++it) {
    int rloc = w * 32 + it * 16 + lrow;
    int kgf = sl ^ ((rloc >> 1) & 3);
    int rl = min(m0 + rloc, cntE - 1);
    int tok = (e == NE) ? rl : tokens[e * T_TOK + rl];
    aoff[it] = ((size_t)tok * HD + (size_t)kgf * 8) * 2;
    boff[it] = ((size_t)(n0 + rloc) * HD + (size_t)kgf * 8) * 2;
  }

  f32x4 accg[4][4], accu[4][4];
  const f32x4 z4 = {0.f, 0.f, 0.f, 0.f};
  #pragma unroll
  for (int i = 0; i < 4; ++i)
    #pragma unroll
    for (int j = 0; j < 4; ++j) { accg[i][j] = z4; accu[i][j] = z4; }

  const int lr = lane & 15, lg = lane >> 4;
  const int wm = (w >> 1) * 64, wn = (w & 1) * 64;

  #define STAGE1(ks, b) { \
    size_t kb = (size_t)(ks) * (BK1 * 2); \
    _Pragma("unroll") \
    for (int it = 0; it < 2; ++it) { \
      gl16((const char*)xb + aoff[it] + kb, &Al [b][(w * 32 + it * 16) * BK1]); \
      gl16((const char*)Bg + boff[it] + kb, &Bgl[b][(w * 32 + it * 16) * BK1]); \
      gl16((const char*)Bu + boff[it] + kb, &Bul[b][(w * 32 + it * 16) * BK1]); \
    } }

  const int NK = HD / BK1;  // 32
  STAGE1(0, 0);
  STAGE1(1, 1);
  int cur = 0;
  for (int ks = 0; ks < NK; ++ks) {
    // drain this wave's loads for stage ks; leave newest stage (ks+1) in flight
    if (ks < NK - 1) { WAITV(6); } else { WAITV(0); }
    __builtin_amdgcn_s_barrier();
    if (ks + 2 < NK) { int nb = cur + 2; if (nb >= 3) nb -= 3; STAGE1(ks + 2, nb); }
    bf16x8 a[4], bg[4], bu[4];
    #pragma unroll
    for (int am = 0; am < 4; ++am) {
      int r = wm + am * 16 + lr;
      a[am] = *(const bf16x8*)&Al[cur][r * BK1 + ((lg ^ ((r >> 1) & 3)) * 8)];
    }
    #pragma unroll
    for (int bn = 0; bn < 4; ++bn) {
      int c = wn + bn * 16 + lr;
      int so = c * BK1 + ((lg ^ ((c >> 1) & 3)) * 8);
      bg[bn] = *(const bf16x8*)&Bgl[cur][so];
      bu[bn] = *(const bf16x8*)&Bul[cur][so];
    }
    #pragma unroll
    for (int bn = 0; bn < 4; ++bn)
      #pragma unroll
      for (int am = 0; am < 4; ++am) {
        accg[am][bn] = __builtin_amdgcn_mfma_f32_16x16x32_bf16(a[am], bg[bn], accg[am][bn], 0, 0, 0);
        accu[am][bn] = __builtin_amdgcn_mfma_f32_16x16x32_bf16(a[am], bu[bn], accu[am][bn], 0, 0, 0);
      }
    cur = (cur == 2) ? 0 : cur + 1;
  }
  #undef STAGE1

  #pragma unroll
  for (int am = 0; am < 4; ++am) {
    #pragma unroll
    for (int bn = 0; bn < 4; ++bn) {
      f32x4 gv = accg[am][bn], uv = accu[am][bn];
      int col = n0 + wn + bn * 16 + lr;
      #pragma unroll
      for (int q = 0; q < 4; ++q) {
        int r = wm + am * 16 + lg * 4 + q;
        if (m0 + r < cntE) {
          float g = gv[q], u = uv[q];
          float val = (g / (1.f + __expf(-g))) * u;
          act[(size_t)(rowbase + m0 + r) * ID + col] = f2bf(val);
        }
      }
    }
  }
}

// ---------------- GEMM2: dn[slot] = act[slot] @ Wd, 3-buf counted-vmcnt, BK=32 ----------------
__global__ __launch_bounds__(256) void k_mlp2(
    const unsigned short* __restrict__ act,
    const unsigned short* __restrict__ WdT, const unsigned short* __restrict__ SdT,
    const int* __restrict__ cnt, const int* __restrict__ base,
    unsigned short* __restrict__ dn)
{
  __shared__ __attribute__((aligned(16))) unsigned short Al[3][BM * BK1];
  __shared__ __attribute__((aligned(16))) unsigned short Bl[3][BN * BK1];
  const int e = blockIdx.z;
  const int cntE = (e == NE) ? T_TOK : cnt[e];
  const int m0 = blockIdx.y * BM;
  if (m0 >= cntE) return;
  const int n0 = blockIdx.x * BN;
  const unsigned short* B = (e == NE) ? SdT : WdT + (size_t)e * ID * HD;
  const int rowbase = (e == NE) ? 2 * T_TOK : base[e];
  const int tid = threadIdx.x, lane = tid & 63, w = tid >> 6;
  const int sl = lane & 3;
  const int lrow = lane >> 2;

  size_t aoff[2], boff[2];
  #pragma unroll
  for (int it = 0; it < 2; ++it) {
    int rloc = w * 32 + it * 16 + lrow;
    int kgf = sl ^ ((rloc >> 1) & 3);
    int rl = rowbase + min(m0 + rloc, cntE - 1);
    aoff[it] = ((size_t)rl * ID + (size_t)kgf * 8) * 2;
    boff[it] = ((size_t)(n0 + rloc) * ID + (size_t)kgf * 8) * 2;
  }

  f32x4 acc[4][4];
  const f32x4 z4 = {0.f, 0.f, 0.f, 0.f};
  #pragma unroll
  for (int i = 0; i < 4; ++i)
    #pragma unroll
    for (int j = 0; j < 4; ++j) acc[i][j] = z4;

  const int lr = lane & 15, lg = lane >> 4;
  const int wm = (w >> 1) * 64, wn = (w & 1) * 64;

  #define STAGE2(ks, b) { \
    size_t kb = (size_t)(ks) * (BK1 * 2); \
    _Pragma("unroll") \
    for (int it = 0; it < 2; ++it) { \
      gl16((const char*)act + aoff[it] + kb, &Al[b][(w * 32 + it * 16) * BK1]); \
      gl16((const char*)B   + boff[it] + kb, &Bl[b][(w * 32 + it * 16) * BK1]); \
    } }

  const int NK = ID / BK1;  // 64
  STAGE2(0, 0);
  STAGE2(1, 1);
  int cur = 0;
  for (int ks = 0; ks < NK; ++ks) {
    if (ks < NK - 1) { WAITV(4); } else { WAITV(0); }
    __builtin_amdgcn_s_barrier();
    if (ks + 2 < NK) { int nb = cur + 2; if (nb >= 3) nb -= 3; STAGE2(ks + 2, nb); }
    bf16x8 a[4], b[4];
    #pragma unroll
    for (int am = 0; am < 4; ++am) {
      int r = wm + am * 16 + lr;
      a[am] = *(const bf16x8*)&Al[cur][r * BK1 + ((lg ^ ((r >> 1) & 3)) * 8)];
    }
    #pragma unroll
    for (int bn = 0; bn < 4; ++bn) {
      int c = wn + bn * 16 + lr;
      b[bn] = *(const bf16x8*)&Bl[cur][c * BK1 + ((lg ^ ((c >> 1) & 3)) * 8)];
    }
    #pragma unroll
    for (int bn = 0; bn < 4; ++bn)
      #pragma unroll
      for (int am = 0; am < 4; ++am)
        acc[am][bn] = __builtin_amdgcn_mfma_f32_16x16x32_bf16(a[am], b[bn], acc[am][bn], 0, 0, 0);
    cur = (cur == 2) ? 0 : cur + 1;
  }
  #undef STAGE2

  #pragma unroll
  for (int am = 0; am < 4; ++am) {
    #pragma unroll
    for (int bn = 0; bn < 4; ++bn) {
      f32x4 av = acc[am][bn];
      int col = n0 + wn + bn * 16 + lr;
      #pragma unroll
      for (int q = 0; q < 4; ++q) {
        int r = wm + am * 16 + lg * 4 + q;
        if (m0 + r < cntE)
          dn[(size_t)(rowbase + m0 + r) * HD + col] = f2bf(av[q]);
      }
    }
  }
}

// ---------------- combine: out[t] = dn[shared_t] + w1*dn[s1] + w2*dn[s2] ----------------
__global__ __launch_bounds__(256) void k_comb(const unsigned short* __restrict__ dn,
    const int* __restrict__ base, const int* __restrict__ slotrec,
    const float* __restrict__ wts, float* __restrict__ out)
{
  const int t = blockIdx.x;
  const int c = threadIdx.x * 4;
  int r0 = slotrec[t * 2], r1 = slotrec[t * 2 + 1];
  int e0 = r0 >> 16, p0 = r0 & 0xffff;
  int e1 = r1 >> 16, p1 = r1 & 0xffff;
  int s0 = base[e0] + p0, s1 = base[e1] + p1;
  float w0 = wts[e0 * T_TOK + p0], w1 = wts[e1 * T_TOK + p1];
  u32x2 vs = *(const u32x2*)&dn[(size_t)(2 * T_TOK + t) * HD + c];
  u32x2 va = *(const u32x2*)&dn[(size_t)s0 * HD + c];
  u32x2 vb = *(const u32x2*)&dn[(size_t)s1 * HD + c];
  f32x4 o;
  o[0] = bflo(vs[0]) + w0 * bflo(va[0]) + w1 * bflo(vb[0]);
  o[1] = bfhi(vs[0]) + w0 * bfhi(va[0]) + w1 * bfhi(vb[0]);
  o[2] = bflo(vs[1]) + w0 * bflo(va[1]) + w1 * bflo(vb[1]);
  o[3] = bfhi(vs[1]) + w0 * bfhi(va[1]) + w1 * bfhi(vb[1]);
  *(f32x4*)&out[(size_t)t * HD + c] = o;
}

extern "C" void kernel_launch(void* const* d_in, const int* in_sizes, int n_in,
                              void* d_out, int out_size, void* d_ws, size_t ws_size,
                              hipStream_t stream)
{
  const float* x    = (const float*)d_in[0];
  const float* gw   = (const float*)d_in[1];
  const float* bias = (const float*)d_in[2];
  const float* Wg   = (const float*)d_in[3];
  const float* Wu   = (const float*)d_in[4];
  const float* Wd   = (const float*)d_in[5];
  const float* Sg   = (const float*)d_in[6];
  const float* Su   = (const float*)d_in[7];
  const float* Sd   = (const float*)d_in[8];
  float* out = (float*)d_out;
  char* ws = (char*)d_ws;

  int*   cnt     = (int*)ws;
  int*   base    = cnt + 16;
  int*   tokens  = (int*)(ws + 512);
  float* wts     = (float*)(ws + 512 + (NE * T_TOK * 4));
  int*   slotrec = (int*)(ws + 512 + 2 * (NE * T_TOK * 4));

  size_t o = (size_t)1 << 20;
  unsigned short* xbf = (unsigned short*)(ws + o); o += (size_t)T_TOK * HD * 2;
  unsigned short* WgT = (unsigned short*)(ws + o); o += (size_t)NE * HD * ID * 2;
  unsigned short* WuT = (unsigned short*)(ws + o); o += (size_t)NE * HD * ID * 2;
  unsigned short* WdT = (unsigned short*)(ws + o); o += (size_t)NE * HD * ID * 2;
  unsigned short* SgT = (unsigned short*)(ws + o); o += (size_t)HD * ID * 2;
  unsigned short* SuT = (unsigned short*)(ws + o); o += (size_t)HD * ID * 2;
  unsigned short* SdT = (unsigned short*)(ws + o); o += (size_t)HD * ID * 2;
  unsigned short* actb = (unsigned short*)(ws + o); o += (size_t)3 * T_TOK * ID * 2;
  unsigned short* dn   = (unsigned short*)(ws + o);   // 12288 x 1024 bf16 (24MB)

  k_zero<<<dim3(1), dim3(64), 0, stream>>>(cnt);
  k_cvtx<<<dim3(T_TOK * HD / 2048), dim3(256), 0, stream>>>(x, xbf);
  k_tcvt<<<dim3(ID / 64, HD / 64, NE), dim3(256), 0, stream>>>(Wg, WgT, HD, ID);
  k_tcvt<<<dim3(ID / 64, HD / 64, NE), dim3(256), 0, stream>>>(Wu, WuT, HD, ID);
  k_tcvt<<<dim3(HD / 64, ID / 64, NE), dim3(256), 0, stream>>>(Wd, WdT, ID, HD);
  k_tcvt<<<dim3(ID / 64, HD / 64, 1),  dim3(256), 0, stream>>>(Sg, SgT, HD, ID);
  k_tcvt<<<dim3(ID / 64, HD / 64, 1),  dim3(256), 0, stream>>>(Su, SuT, HD, ID);
  k_tcvt<<<dim3(HD / 64, ID / 64, 1),  dim3(256), 0, stream>>>(Sd, SdT, ID, HD);
  k_route<<<dim3(T_TOK / 4), dim3(256), 0, stream>>>(x, gw, bias, cnt, tokens, wts, slotrec);
  k_fin<<<dim3(1), dim3(64), 0, stream>>>(cnt, base, out);
  k_mlp1<<<dim3(ID / BN, T_TOK / BM, NE + 1), dim3(256), 0, stream>>>(xbf, WgT, WuT, SgT, SuT, cnt, base, tokens, actb);
  k_mlp2<<<dim3(HD / BN, T_TOK / BM, NE + 1), dim3(256), 0, stream>>>(actb, WdT, SdT, cnt, base, dn);
  k_comb<<<dim3(T_TOK), dim3(256), 0, stream>>>(dn, base, slotrec, wts, out);
}

// Round 5
// 417.515 us; speedup vs baseline: 1.5758x; 1.1378x over previous
//
#include <hip/hip_runtime.h>
#include <hip/hip_bf16.h>

#define T_TOK 4096
#define HD 1024
#define ID 2048
#define NE 8

typedef __attribute__((ext_vector_type(8))) __bf16 bf16x8;
typedef __attribute__((ext_vector_type(4))) float f32x4;
typedef __attribute__((ext_vector_type(4))) unsigned int u32x4;
typedef __attribute__((ext_vector_type(2))) unsigned int u32x2;

#define AS1 __attribute__((address_space(1)))
#define AS3 __attribute__((address_space(3)))

#define WAITV(N) asm volatile("s_waitcnt vmcnt(" #N ")" ::: "memory")
#define BAR()    asm volatile("s_barrier" ::: "memory")
#define LGKM0()  { asm volatile("s_waitcnt lgkmcnt(0)" ::: "memory"); __builtin_amdgcn_sched_barrier(0); }

__device__ __forceinline__ unsigned short f2bf(float f) {
  __hip_bfloat16 h = __float2bfloat16(f);
  return __builtin_bit_cast(unsigned short, h);
}
__device__ __forceinline__ unsigned int pk2(float lo, float hi) {
  return (unsigned int)f2bf(lo) | ((unsigned int)f2bf(hi) << 16);
}
__device__ __forceinline__ float bflo(unsigned int u) { return __builtin_bit_cast(float, u << 16); }
__device__ __forceinline__ float bfhi(unsigned int u) { return __builtin_bit_cast(float, u & 0xffff0000u); }
__device__ __forceinline__ void gl16(const void* g, void* l) {
  __builtin_amdgcn_global_load_lds((const AS1 unsigned int*)g, (AS3 unsigned int*)l, 16, 0, 0);
}

// ---------------- routing ----------------
__global__ void k_zero(int* cnt) { if (threadIdx.x < 32) cnt[threadIdx.x] = 0; }

__global__ __launch_bounds__(256) void k_route(const float* __restrict__ x,
    const float* __restrict__ gw, const float* __restrict__ bias,
    int* __restrict__ cnt, int* __restrict__ tokens, float* __restrict__ wts,
    int* __restrict__ slotrec)
{
  const int lane = threadIdx.x & 63;
  const int t = blockIdx.x * 4 + (threadIdx.x >> 6);
  const float* xr = x + (size_t)t * HD + lane * 16;
  f32x4 xv[4];
  #pragma unroll
  for (int j = 0; j < 4; ++j) xv[j] = *(const f32x4*)(xr + j * 4);
  float sc[NE];
  #pragma unroll
  for (int e = 0; e < NE; ++e) {
    const float* gr = gw + e * HD + lane * 16;
    float a = 0.f;
    #pragma unroll
    for (int j = 0; j < 4; ++j) {
      f32x4 gv = *(const f32x4*)(gr + j * 4);
      a += xv[j][0]*gv[0] + xv[j][1]*gv[1] + xv[j][2]*gv[2] + xv[j][3]*gv[3];
    }
    #pragma unroll
    for (int off = 32; off > 0; off >>= 1) a += __shfl_xor(a, off);
    sc[e] = a;
  }
  int i1 = 0; float b1 = sc[0] + bias[0];
  #pragma unroll
  for (int e = 1; e < NE; ++e) { float be = sc[e] + bias[e]; if (be > b1) { b1 = be; i1 = e; } }
  int i2 = -1; float b2 = -3e38f;
  #pragma unroll
  for (int e = 0; e < NE; ++e) { if (e == i1) continue; float be = sc[e] + bias[e]; if (be > b2) { b2 = be; i2 = e; } }
  int a1 = 0; float r1 = sc[0];
  #pragma unroll
  for (int e = 1; e < NE; ++e) if (sc[e] > r1) { r1 = sc[e]; a1 = e; }
  float r2 = -3e38f;
  #pragma unroll
  for (int e = 0; e < NE; ++e) if (e != a1 && sc[e] > r2) r2 = sc[e];
  float w1 = 1.f / (1.f + __expf(-r1));
  float w2 = 1.f / (1.f + __expf(-r2));
  float s = w1 + w2; w1 /= s; w2 /= s;
  if (lane == 0) {
    int p = atomicAdd(&cnt[i1], 1); tokens[i1 * T_TOK + p] = t; wts[i1 * T_TOK + p] = w1;
    slotrec[t * 2] = (i1 << 16) | p;
    p = atomicAdd(&cnt[i2], 1);     tokens[i2 * T_TOK + p] = t; wts[i2 * T_TOK + p] = w2;
    slotrec[t * 2 + 1] = (i2 << 16) | p;
  }
}

__global__ void k_fin(const int* __restrict__ cnt, int* __restrict__ base, float* __restrict__ out)
{
  if (threadIdx.x == 0) {
    int b = 0, mx = 0;
    #pragma unroll
    for (int e = 0; e < NE; ++e) { base[e] = b; b += cnt[e]; if (cnt[e] > mx) mx = cnt[e]; }
    base[NE] = b;
    out[(size_t)T_TOK * HD] = (float)mx * (1.f / 1024.f) - 1.f;  // viol
  }
}

// ---------------- converts ----------------
__global__ __launch_bounds__(256) void k_cvtx(const float* __restrict__ x, unsigned short* __restrict__ xb) {
  size_t i = ((size_t)blockIdx.x * 256 + threadIdx.x) * 8;
  f32x4 v0 = *(const f32x4*)(x + i), v1 = *(const f32x4*)(x + i + 4);
  u32x4 pk = { pk2(v0[0],v0[1]), pk2(v0[2],v0[3]), pk2(v1[0],v1[1]), pk2(v1[2],v1[3]) };
  *(u32x4*)&xb[i] = pk;
}

// src [K][N] fp32 -> dst [vmap(N)][K] bf16. mode 0: v=n; mode 1: gate interleave; mode 2: up.
__global__ __launch_bounds__(256) void k_tcvt(const float* __restrict__ src0, unsigned short* __restrict__ dst0,
                                              int K, int N, long zsrc, long zdst, int mode)
{
  __shared__ __attribute__((aligned(16))) unsigned short tl[64 * 64];
  const float* src = src0 + (size_t)blockIdx.z * zsrc;
  unsigned short* dst = dst0 + (size_t)blockIdx.z * zdst;
  const int k0 = blockIdx.y * 64, n0 = blockIdx.x * 64;
  const int t = threadIdx.x;
  const int nc = (t & 15) * 4;
  #pragma unroll
  for (int it = 0; it < 4; ++it) {
    int kr = (t >> 4) + it * 16;
    f32x4 v = *(const f32x4*)&src[(size_t)(k0 + kr) * N + n0 + nc];
    #pragma unroll
    for (int j = 0; j < 4; ++j) {
      int n = nc + j;
      tl[n * 64 + (((kr >> 3) ^ (n & 7)) * 8) + (kr & 7)] = f2bf(v[j]);
    }
  }
  __syncthreads();
  #pragma unroll
  for (int it = 0; it < 2; ++it) {
    int idx = t + it * 256;
    int n = idx >> 3, kc8 = idx & 7;
    u32x4 v = *(const u32x4*)&tl[n * 64 + ((kc8 ^ (n & 7)) * 8)];
    int nn = n0 + n;
    int vrow = (mode == 0) ? nn : (((nn >> 5) << 6) + (nn & 31) + ((mode == 2) ? 32 : 0));
    *(u32x4*)&dst[(size_t)vrow * K + k0 + kc8 * 8] = v;
  }
}

// ================= GEMM1: 256x256 virtual (gate|up interleaved), 8-phase =================
// LDS slot: A [256][64], B [256][64]; chunk s of row r holds k-group s^(r&7) (pre-swizzled src).
__global__ __launch_bounds__(512, 2) void k_mlp1(
    const unsigned short* __restrict__ xb,
    const unsigned short* __restrict__ Wgu, const unsigned short* __restrict__ Sgu,
    const int* __restrict__ cnt, const int* __restrict__ base, const int* __restrict__ tokens,
    unsigned short* __restrict__ act)
{
  __shared__ __attribute__((aligned(16))) unsigned short Abuf[2][16384];
  __shared__ __attribute__((aligned(16))) unsigned short Bbuf[2][16384];

  const int e = blockIdx.z;
  const int cntE = (e == NE) ? T_TOK : cnt[e];
  const int m0 = blockIdx.y * 256;
  if (m0 >= cntE) return;
  const int n0 = blockIdx.x * 256;                       // virtual col base
  const unsigned short* Bsrc = (e == NE) ? Sgu : Wgu + (size_t)e * 4096 * 1024;
  const int rowbase = (e == NE) ? 2 * T_TOK : base[e];
  const int tid = threadIdx.x, lane = tid & 63, w = tid >> 6;
  const int srow = tid >> 3;                             // 0..63
  const int kgf = (tid & 7) ^ (srow & 7);                // pre-swizzled fetch k-group

  const unsigned short* asrc[4]; const unsigned short* bsrc[4];
  #pragma unroll
  for (int u = 0; u < 4; ++u) {
    int r = u * 64 + srow;
    int rl = min(m0 + r, cntE - 1);
    int tok = (e == NE) ? rl : tokens[e * T_TOK + rl];
    asrc[u] = xb + (size_t)tok * HD + kgf * 8;
    bsrc[u] = Bsrc + (size_t)(n0 + r) * HD + kgf * 8;
  }

  f32x4 acc[8][4];
  const f32x4 z4 = {0.f, 0.f, 0.f, 0.f};
  #pragma unroll
  for (int i = 0; i < 8; ++i)
    #pragma unroll
    for (int j = 0; j < 4; ++j) acc[i][j] = z4;

  const int lr = lane & 15, lg = lane >> 4;
  const int wm = (w >> 2) * 128;                         // 2 M-wave groups
  const int wn4 = (w & 3) * 64;                          // 4 N-waves
  const int ck0 = (lg ^ (lr & 7)) * 16;
  const int arow0 = (wm + lr) * 128;
  const int brow0 = (wn4 + lr) * 128;

  bf16x8 af[4][2], bf[2][2][2];

  // stage: half h_ (128 rows) of tile t_ into slot s_ (2 x gl16 per thread)
  #define SA1(t_, h_, s_) { \
    gl16(asrc[(h_)*2+0] + (t_)*64, &Abuf[s_][(h_)*8192 + 0    + w*512]); \
    gl16(asrc[(h_)*2+1] + (t_)*64, &Abuf[s_][(h_)*8192 + 4096 + w*512]); }
  #define SB1(t_, h_, s_) { \
    gl16(bsrc[(h_)*2+0] + (t_)*64, &Bbuf[s_][(h_)*8192 + 0    + w*512]); \
    gl16(bsrc[(h_)*2+1] + (t_)*64, &Bbuf[s_][(h_)*8192 + 4096 + w*512]); }
  #define LDA1(s_, mh_) { _Pragma("unroll") for (int am_ = 0; am_ < 4; ++am_) { \
    af[am_][0] = *(const bf16x8*)((const char*)&Abuf[s_][0] + arow0 + (mh_)*8192 + am_*2048 + ck0); \
    af[am_][1] = *(const bf16x8*)((const char*)&Abuf[s_][0] + arow0 + (mh_)*8192 + am_*2048 + (ck0^64)); } }
  #define LDB1(s_, nh_) { _Pragma("unroll") for (int bn_ = 0; bn_ < 2; ++bn_) { \
    bf[nh_][bn_][0] = *(const bf16x8*)((const char*)&Bbuf[s_][0] + brow0 + (nh_)*4096 + bn_*2048 + ck0); \
    bf[nh_][bn_][1] = *(const bf16x8*)((const char*)&Bbuf[s_][0] + brow0 + (nh_)*4096 + bn_*2048 + (ck0^64)); } }
  #define MM1(mh_, nh_) { __builtin_amdgcn_s_setprio(1); \
    _Pragma("unroll") for (int bn_ = 0; bn_ < 2; ++bn_) \
      _Pragma("unroll") for (int am_ = 0; am_ < 4; ++am_) { \
        acc[(mh_)*4+am_][(nh_)*2+bn_] = __builtin_amdgcn_mfma_f32_16x16x32_bf16(af[am_][0], bf[nh_][bn_][0], acc[(mh_)*4+am_][(nh_)*2+bn_], 0,0,0); \
        acc[(mh_)*4+am_][(nh_)*2+bn_] = __builtin_amdgcn_mfma_f32_16x16x32_bf16(af[am_][1], bf[nh_][bn_][1], acc[(mh_)*4+am_][(nh_)*2+bn_], 0,0,0); } \
    __builtin_amdgcn_s_setprio(0); }

  const int NT = 16;  // K=1024 / 64
  // prologue: tile0 all halves + tile1 B halves (A(1) staged in-loop at P1/P2 of t=0)
  SA1(0, 0, 0); SA1(0, 1, 0); SB1(0, 0, 0); SB1(0, 1, 0);
  SB1(1, 0, 1); SB1(1, 1, 1);
  WAITV(4);
  BAR();

  // 4 phases per tile; snake quadrants (m0n0, m0n1, m1n1, m1n0)
  #define TILE1(t_, s_, o_) { \
    /* P1 */ LDA1(s_, 0); LDB1(s_, 0); if ((t_)+1 < NT) SA1((t_)+1, 0, o_); \
    BAR(); LGKM0(); MM1(0, 0); BAR(); \
    /* P2 */ LDB1(s_, 1); if ((t_)+1 < NT) SA1((t_)+1, 1, o_); \
    BAR(); LGKM0(); MM1(0, 1); BAR(); \
    /* P3 */ LDA1(s_, 1); if ((t_)+2 < NT) SB1((t_)+2, 0, s_); \
    BAR(); LGKM0(); MM1(1, 1); BAR(); \
    /* P4 */ if ((t_)+2 < NT) SB1((t_)+2, 1, s_); \
    BAR(); LGKM0(); MM1(1, 0); WAITV(4); BAR(); }

  for (int t = 0; t < NT; t += 2) {
    TILE1(t, 0, 1);
    TILE1(t + 1, 1, 0);
  }
  #undef TILE1
  #undef SA1
  #undef SB1
  #undef LDA1
  #undef LDB1
  #undef MM1

  // epilogue: pair gate frags (nf 0,1) with up frags (nf 2,3)
  const int colbase = ((n0 + wn4) >> 1);
  #pragma unroll
  for (int mf = 0; mf < 8; ++mf) {
    const int rloc = wm + (mf >> 2) * 64 + (mf & 3) * 16 + lg * 4;
    #pragma unroll
    for (int p = 0; p < 2; ++p) {
      f32x4 gv = acc[mf][p], uv = acc[mf][p + 2];
      int col = colbase + p * 16 + lr;
      #pragma unroll
      for (int q = 0; q < 4; ++q) {
        int r = rloc + q;
        if (m0 + r < cntE) {
          float g = gv[q], u = uv[q];
          act[(size_t)(rowbase + m0 + r) * ID + col] = f2bf((g / (1.f + __expf(-g))) * u);
        }
      }
    }
  }
}

// ================= GEMM2: 256x128, 8-phase =================
__global__ __launch_bounds__(512, 2) void k_mlp2(
    const unsigned short* __restrict__ act,
    const unsigned short* __restrict__ WdT, const unsigned short* __restrict__ SdT,
    const int* __restrict__ cnt, const int* __restrict__ base,
    unsigned short* __restrict__ dn)
{
  __shared__ __attribute__((aligned(16))) unsigned short Abuf[2][16384];  // 256x64
  __shared__ __attribute__((aligned(16))) unsigned short Bbuf[2][8192];   // 128x64

  const int e = blockIdx.z;
  const int cntE = (e == NE) ? T_TOK : cnt[e];
  const int m0 = blockIdx.y * 256;
  if (m0 >= cntE) return;
  const int n0 = blockIdx.x * 128;
  const unsigned short* Bsrc = (e == NE) ? SdT : WdT + (size_t)e * ID * HD;
  const int rowbase = (e == NE) ? 2 * T_TOK : base[e];
  const int tid = threadIdx.x, lane = tid & 63, w = tid >> 6;
  const int srow = tid >> 3;
  const int kgf = (tid & 7) ^ (srow & 7);

  const unsigned short* asrc[4]; const unsigned short* bsrc[2];
  #pragma unroll
  for (int u = 0; u < 4; ++u) {
    int r = u * 64 + srow;
    int rl = rowbase + min(m0 + r, cntE - 1);
    asrc[u] = act + (size_t)rl * ID + kgf * 8;
  }
  #pragma unroll
  for (int u = 0; u < 2; ++u)
    bsrc[u] = Bsrc + (size_t)(n0 + u * 64 + srow) * ID + kgf * 8;

  f32x4 acc[4][4];
  const f32x4 z4 = {0.f, 0.f, 0.f, 0.f};
  #pragma unroll
  for (int i = 0; i < 4; ++i)
    #pragma unroll
    for (int j = 0; j < 4; ++j) acc[i][j] = z4;

  const int lr = lane & 15, lg = lane >> 4;
  const int wm2 = (w >> 1) * 64;                 // 4 M-waves
  const int wn2 = (w & 1) * 64;                  // 2 N-waves
  const int ck0 = (lg ^ (lr & 7)) * 16;
  const int arow0 = (wm2 + lr) * 128;
  const int brow0 = (wn2 + lr) * 128;

  bf16x8 af[2][2], bf[2][2][2];

  #define SA2(t_, h_, s_) { \
    gl16(asrc[(h_)*2+0] + (t_)*64, &Abuf[s_][(h_)*8192 + 0    + w*512]); \
    gl16(asrc[(h_)*2+1] + (t_)*64, &Abuf[s_][(h_)*8192 + 4096 + w*512]); }
  #define SB2(t_, s_) { \
    gl16(bsrc[0] + (t_)*64, &Bbuf[s_][0    + w*512]); \
    gl16(bsrc[1] + (t_)*64, &Bbuf[s_][4096 + w*512]); }
  #define LDA2(s_, mh_) { _Pragma("unroll") for (int am_ = 0; am_ < 2; ++am_) { \
    af[am_][0] = *(const bf16x8*)((const char*)&Abuf[s_][0] + arow0 + (mh_)*4096 + am_*2048 + ck0); \
    af[am_][1] = *(const bf16x8*)((const char*)&Abuf[s_][0] + arow0 + (mh_)*4096 + am_*2048 + (ck0^64)); } }
  #define LDB2(s_, nh_) { _Pragma("unroll") for (int bn_ = 0; bn_ < 2; ++bn_) { \
    bf[nh_][bn_][0] = *(const bf16x8*)((const char*)&Bbuf[s_][0] + brow0 + (nh_)*4096 + bn_*2048 + ck0); \
    bf[nh_][bn_][1] = *(const bf16x8*)((const char*)&Bbuf[s_][0] + brow0 + (nh_)*4096 + bn_*2048 + (ck0^64)); } }
  #define MM2(mh_, nh_) { __builtin_amdgcn_s_setprio(1); \
    _Pragma("unroll") for (int bn_ = 0; bn_ < 2; ++bn_) \
      _Pragma("unroll") for (int am_ = 0; am_ < 2; ++am_) { \
        acc[(mh_)*2+am_][(nh_)*2+bn_] = __builtin_amdgcn_mfma_f32_16x16x32_bf16(af[am_][0], bf[nh_][bn_][0], acc[(mh_)*2+am_][(nh_)*2+bn_], 0,0,0); \
        acc[(mh_)*2+am_][(nh_)*2+bn_] = __builtin_amdgcn_mfma_f32_16x16x32_bf16(af[am_][1], bf[nh_][bn_][1], acc[(mh_)*2+am_][(nh_)*2+bn_], 0,0,0); } \
    __builtin_amdgcn_s_setprio(0); }

  const int NT = 32;  // K=2048 / 64
  // prologue: tile0 (A both halves + B) + A-half0 of tile1
  SA2(0, 0, 0); SA2(0, 1, 0); SB2(0, 0);
  SA2(1, 0, 1);
  WAITV(2);
  BAR();

  #define TILE2(t_, s_, o_) { \
    /* P1 */ LDA2(s_, 0); LDB2(s_, 0); if ((t_)+1 < NT) { SB2((t_)+1, o_); SA2((t_)+1, 1, o_); } \
    BAR(); LGKM0(); MM2(0, 0); BAR(); \
    /* P2 */ LDB2(s_, 1); \
    BAR(); LGKM0(); MM2(0, 1); BAR(); \
    /* P3 */ LDA2(s_, 1); \
    BAR(); LGKM0(); MM2(1, 1); BAR(); \
    /* P4 */ if ((t_)+2 < NT) SA2((t_)+2, 0, s_); \
    BAR(); LGKM0(); MM2(1, 0); WAITV(2); BAR(); }

  for (int t = 0; t < NT; t += 2) {
    TILE2(t, 0, 1);
    TILE2(t + 1, 1, 0);
  }
  #undef TILE2
  #undef SA2
  #undef SB2
  #undef LDA2
  #undef LDB2
  #undef MM2

  #pragma unroll
  for (int mf = 0; mf < 4; ++mf) {
    const int rloc = wm2 + (mf >> 1) * 32 + (mf & 1) * 16 + lg * 4;
    #pragma unroll
    for (int nf = 0; nf < 4; ++nf) {
      f32x4 av = acc[mf][nf];
      int col = n0 + wn2 + nf * 16 + lr;
      #pragma unroll
      for (int q = 0; q < 4; ++q) {
        int r = rloc + q;
        if (m0 + r < cntE)
          dn[(size_t)(rowbase + m0 + r) * HD + col] = f2bf(av[q]);
      }
    }
  }
}

// ---------------- combine: out[t] = dn[shared_t] + w1*dn[s1] + w2*dn[s2] ----------------
__global__ __launch_bounds__(256) void k_comb(const unsigned short* __restrict__ dn,
    const int* __restrict__ base, const int* __restrict__ slotrec,
    const float* __restrict__ wts, float* __restrict__ out)
{
  const int t = blockIdx.x;
  const int c = threadIdx.x * 4;
  int r0 = slotrec[t * 2], r1 = slotrec[t * 2 + 1];
  int e0 = r0 >> 16, p0 = r0 & 0xffff;
  int e1 = r1 >> 16, p1 = r1 & 0xffff;
  int s0 = base[e0] + p0, s1 = base[e1] + p1;
  float w0 = wts[e0 * T_TOK + p0], w1 = wts[e1 * T_TOK + p1];
  u32x2 vs = *(const u32x2*)&dn[(size_t)(2 * T_TOK + t) * HD + c];
  u32x2 va = *(const u32x2*)&dn[(size_t)s0 * HD + c];
  u32x2 vb = *(const u32x2*)&dn[(size_t)s1 * HD + c];
  f32x4 o;
  o[0] = bflo(vs[0]) + w0 * bflo(va[0]) + w1 * bflo(vb[0]);
  o[1] = bfhi(vs[0]) + w0 * bfhi(va[0]) + w1 * bfhi(vb[0]);
  o[2] = bflo(vs[1]) + w0 * bflo(va[1]) + w1 * bflo(vb[1]);
  o[3] = bfhi(vs[1]) + w0 * bfhi(va[1]) + w1 * bfhi(vb[1]);
  *(f32x4*)&out[(size_t)t * HD + c] = o;
}

extern "C" void kernel_launch(void* const* d_in, const int* in_sizes, int n_in,
                              void* d_out, int out_size, void* d_ws, size_t ws_size,
                              hipStream_t stream)
{
  const float* x    = (const float*)d_in[0];
  const float* gw   = (const float*)d_in[1];
  const float* bias = (const float*)d_in[2];
  const float* Wg   = (const float*)d_in[3];
  const float* Wu   = (const float*)d_in[4];
  const float* Wd   = (const float*)d_in[5];
  const float* Sg   = (const float*)d_in[6];
  const float* Su   = (const float*)d_in[7];
  const float* Sd   = (const float*)d_in[8];
  float* out = (float*)d_out;
  char* ws = (char*)d_ws;

  int*   cnt     = (int*)ws;
  int*   base    = cnt + 16;
  int*   tokens  = (int*)(ws + 512);
  float* wts     = (float*)(ws + 512 + (NE * T_TOK * 4));
  int*   slotrec = (int*)(ws + 512 + 2 * (NE * T_TOK * 4));

  const size_t MB = (size_t)1 << 20;
  unsigned short* xbf = (unsigned short*)(ws + 1 * MB);    // 8 MB
  unsigned short* WdT = (unsigned short*)(ws + 9 * MB);    // 32 MB
  unsigned short* SdT = (unsigned short*)(ws + 41 * MB);   // 4 MB
  unsigned short* Wgu = (unsigned short*)(ws + 45 * MB);   // 64 MB (dead after mlp1)
  unsigned short* Sgu = (unsigned short*)(ws + 109 * MB);  // 8 MB
  unsigned short* actb = (unsigned short*)(ws + 117 * MB); // 48 MB
  unsigned short* dn  = (unsigned short*)(ws + 45 * MB);   // 24 MB, overlays Wgu

  k_zero<<<dim3(1), dim3(64), 0, stream>>>(cnt);
  k_cvtx<<<dim3(T_TOK * HD / 2048), dim3(256), 0, stream>>>(x, xbf);
  // Wd [2048][1024] -> WdT [1024][2048]
  k_tcvt<<<dim3(16, 32, NE), dim3(256), 0, stream>>>(Wd, WdT, ID, HD, (long)ID * HD, (long)ID * HD, 0);
  k_tcvt<<<dim3(16, 32, 1),  dim3(256), 0, stream>>>(Sd, SdT, ID, HD, 0, 0, 0);
  // Wg/Wu [1024][2048] -> Wgu [4096 virt][1024], interleaved 32-col pairs
  k_tcvt<<<dim3(32, 16, NE), dim3(256), 0, stream>>>(Wg, Wgu, HD, ID, (long)HD * ID, (long)4096 * 1024, 1);
  k_tcvt<<<dim3(32, 16, NE), dim3(256), 0, stream>>>(Wu, Wgu, HD, ID, (long)HD * ID, (long)4096 * 1024, 2);
  k_tcvt<<<dim3(32, 16, 1),  dim3(256), 0, stream>>>(Sg, Sgu, HD, ID, 0, 0, 1);
  k_tcvt<<<dim3(32, 16, 1),  dim3(256), 0, stream>>>(Su, Sgu, HD, ID, 0, 0, 2);
  k_route<<<dim3(T_TOK / 4), dim3(256), 0, stream>>>(x, gw, bias, cnt, tokens, wts, slotrec);
  k_fin<<<dim3(1), dim3(64), 0, stream>>>(cnt, base, out);
  k_mlp1<<<dim3(16, 16, NE + 1), dim3(512), 0, stream>>>(xbf, Wgu, Sgu, cnt, base, tokens, actb);
  k_mlp2<<<dim3(8, 16, NE + 1), dim3(512), 0, stream>>>(actb, WdT, SdT, cnt, base, dn);
  k_comb<<<dim3(T_TOK), dim3(256), 0, stream>>>(dn, base, slotrec, wts, out);
}